// Round 1
// baseline (558.932 us; speedup 1.0000x reference)
//
#include <hip/hip_runtime.h>
#include <cstddef>

#define N_NODES 50000
#define N_EDGES 800000
#define N_PAIRS 100000

typedef float floatx4 __attribute__((ext_vector_type(4)));
typedef _Float16 half2v __attribute__((ext_vector_type(2)));
typedef _Float16 half4v __attribute__((ext_vector_type(4)));
typedef _Float16 half8v __attribute__((ext_vector_type(8)));

// packed MFMA A/B-fragment layout: [tile16][kchunk32][lane][8] (fp16)
__device__ inline size_t packA(int m, int k, int K) {
  return ((size_t)((m >> 4) * (K >> 5) + (k >> 5)) << 9) +
         ((((unsigned)k >> 3) & 3) << 7) + ((m & 15) << 3) + (k & 7);
}

// ---------------- weight prep (fold + transpose + pack, fp16)
__device__ inline float fold_val(int l, int r, int j, const float* Wk, const float* Wq,
                                 const float* Wv, const float* att, const float* msg,
                                 const float* pri) {
  if (j >= 128 && j < 256) return Wq[(l * 128 + r) * 128 + (j - 128)];
  int jj = j & 127, hh = jj >> 4, e = jj & 15;
  const float* W = (j < 128) ? Wk : Wv;
  const float* T = (j < 128) ? att : msg;
  float s = 0.f;
#pragma unroll
  for (int d = 0; d < 16; d++)
    s += W[(l * 128 + r) * 128 + hh * 16 + d] * T[((l * 8 + hh) * 16 + d) * 16 + e];
  if (j < 128) s *= pri[l * 8 + hh] * 0.25f;
  return s;
}

__global__ void wprep_kernel(const float* __restrict__ W_in, const float* __restrict__ Wk,
                             const float* __restrict__ Wq, const float* __restrict__ Wv,
                             const float* __restrict__ att, const float* __restrict__ msg,
                             const float* __restrict__ pri, const float* __restrict__ Wa,
                             const float* __restrict__ W1, const float* __restrict__ W2,
                             _Float16* Wint, _Float16* Wcat, _Float16* Waf,
                             _Float16* W1f, _Float16* W2f) {
  int gid = blockIdx.x * 256 + threadIdx.x;
  float v;
  _Float16* dt;
  size_t o;
  if (gid < 16384) {
    int n = gid >> 7, k = gid & 127;
    v = W_in[k * 128 + n];
    dt = Wint; o = packA(n, k, 128);
  } else if (gid < 163840) {
    int t = gid - 16384;
    int l = t / 49152, u = t - l * 49152;
    int n = u >> 7, k = u & 127;
    v = fold_val(l, k, n, Wk, Wq, Wv, att, msg, pri);
    dt = Wcat + (size_t)l * 49152;
    o = packA(n, k, 128);
  } else if (gid < 212992) {
    int t = gid - 163840;
    int l = t / 16384, u = t & 16383;
    int n = u >> 7, k = u & 127;
    v = Wa[(size_t)l * 16384 + k * 128 + n];
    dt = Waf + (size_t)l * 16384;
    o = packA(n, k, 128);
  } else if (gid < 221184) {
    int u = gid - 212992;
    int n = u >> 7, k = u & 127;
    v = W1[k * 64 + n];
    dt = W1f; o = packA(n, k, 128);
  } else if (gid < 225280) {
    int u = gid - 221184;
    int n = u >> 6, k = u & 63;
    v = (n < 32) ? W2[k * 32 + n] : 0.f;
    dt = W2f; o = packA(n, k, 64);
  } else {
    return;
  }
  dt[o] = (_Float16)v;
}

// ---------------- CSR build (padded to multiple of 8 per node)
__global__ void hist_kernel(const int* __restrict__ dst, int* __restrict__ deg, int E) {
  int g = blockIdx.x * blockDim.x + threadIdx.x;
  if (g < E) atomicAdd(&deg[dst[g]], 1);
}

__global__ void scanA_kernel(const int* __restrict__ deg, int* __restrict__ offs,
                             int* __restrict__ bsum, int n) {
  __shared__ int sm[256];
  int t = threadIdx.x;
  int i = blockIdx.x * 256 + t;
  // pad each node's slot count to a multiple of 8 (half-wave chunk granularity)
  int v = (i < n) ? ((deg[i] + 7) & ~7) : 0;
  sm[t] = v;
  __syncthreads();
  for (int off = 1; off < 256; off <<= 1) {
    int u = (t >= off) ? sm[t - off] : 0;
    __syncthreads();
    sm[t] += u;
    __syncthreads();
  }
  if (i < n) offs[i] = sm[t] - v;
  if (t == 255) bsum[blockIdx.x] = sm[255];
}

__global__ void scanB_kernel(const int* __restrict__ bsum, int* __restrict__ boff,
                             int* __restrict__ offs, int nb, int n) {
  __shared__ int sm[256];
  int t = threadIdx.x;
  int v = (t < nb) ? bsum[t] : 0;
  sm[t] = v;
  __syncthreads();
  for (int off = 1; off < 256; off <<= 1) {
    int u = (t >= off) ? sm[t - off] : 0;
    __syncthreads();
    sm[t] += u;
    __syncthreads();
  }
  boff[t] = sm[t] - v;
  if (t == nb - 1) offs[n] = sm[t];
}

__global__ void scanC_kernel(int* __restrict__ offs, const int* __restrict__ boff,
                             int* __restrict__ cursor, int n) {
  int i = blockIdx.x * 256 + threadIdx.x;
  if (i < n) {
    int o = offs[i] + boff[blockIdx.x];
    offs[i] = o;
    cursor[i] = o;
  }
}

__global__ void scatter_kernel(const int* __restrict__ src, const int* __restrict__ dst,
                               const float* __restrict__ w, int* __restrict__ cursor,
                               int2* __restrict__ eld, int E) {
  int g = blockIdx.x * blockDim.x + threadIdx.x;
  if (g < E) {
    int d = dst[g];
    int p = atomicAdd(&cursor[d], 1);
    eld[p] = make_int2(src[g], __float_as_int(w[g]));
  }
}

// ---------------- degree-descending node permutation (counting sort, 256 buckets)
__global__ void bhist_kernel(const int* __restrict__ deg, int* __restrict__ bh, int n) {
  __shared__ int lh[256];
  int t = threadIdx.x;
  lh[t] = 0;
  __syncthreads();
  int i = blockIdx.x * 256 + t;
  if (i < n) atomicAdd(&lh[min(deg[i], 255)], 1);
  __syncthreads();
  if (lh[t]) atomicAdd(&bh[t], lh[t]);
}
__global__ void bscan_kernel(const int* __restrict__ bh, int* __restrict__ bcur) {
  __shared__ int sm[256];
  int t = threadIdx.x;
  int v = bh[255 - t];
  sm[t] = v;
  __syncthreads();
  for (int off = 1; off < 256; off <<= 1) {
    int u = (t >= off) ? sm[t - off] : 0;
    __syncthreads();
    sm[t] += u;
    __syncthreads();
  }
  bcur[255 - t] = sm[t] - v;
}
__global__ void bscatter_kernel(const int* __restrict__ deg, int* __restrict__ bcur,
                                int* __restrict__ perm, int n) {
  __shared__ int lh[256], lbase[256];
  int t = threadIdx.x;
  lh[t] = 0;
  __syncthreads();
  int i = blockIdx.x * 256 + t;
  int b = 0, local = 0;
  if (i < n) {
    b = min(deg[i], 255);
    local = atomicAdd(&lh[b], 1);
  }
  __syncthreads();
  int cnt = lh[t];
  lbase[t] = cnt ? atomicAdd(&bcur[t], cnt) : 0;
  __syncthreads();
  if (i < n) perm[lbase[b] + local] = i;
}

// ---------------- fused layer kernel: GEMM1 (h) -> LDS fragments -> GEMM2 (kqv)
// FIRST=1: h = relu(x @ Wg1 + bias); FIRST=0: h = mix(agg @ Wg1, hold=hbuf) + relu
// then kqv = h @ Wcat -> kwmv/qbuf; h also written packed to hbuf (next layer's hold)
template <int FIRST>
__global__ __launch_bounds__(256) void fused_layer(
    const float* __restrict__ x, const _Float16* __restrict__ aggp,
    const _Float16* __restrict__ Wg1, const float* __restrict__ bias,
    const float* __restrict__ skipv, _Float16* __restrict__ hbuf,
    const _Float16* __restrict__ Wcat_l,
    _Float16* __restrict__ kwmv, _Float16* __restrict__ qbuf, int M) {
  int tid = threadIdx.x;
  int wave = tid >> 6, lane = tid & 63;
  int l16 = lane & 15, q = lane >> 4;
  int g = q, mloc = l16;
  int tile = blockIdx.x * 4 + wave;
  int m0 = tile * 16;
  bool alive = m0 < M;
  int tileC = alive ? tile : 0;

  __shared__ _Float16 htile_s[4][2048];
  __shared__ float ldsT_s[4][16 * 68];
  _Float16* htile = htile_s[wave];
  float* myT = ldsT_s[wave];

  // GEMM1 A fragments
  half8v a[4];
#pragma unroll
  for (int kc = 0; kc < 4; kc++) {
    if (FIRST) {
      int row = min(m0 + l16, M - 1);
      const float* p = x + (size_t)row * 128 + kc * 32 + q * 8;
      float4 u0 = *(const float4*)p, u1 = *(const float4*)(p + 4);
      float f[8] = {u0.x, u0.y, u0.z, u0.w, u1.x, u1.y, u1.z, u1.w};
      half8v hv;
#pragma unroll
      for (int i = 0; i < 8; i++) hv[i] = (_Float16)f[i];
      a[kc] = hv;
    } else {
      a[kc] = *(const half8v*)(aggp + (size_t)tileC * 2048 + (kc << 9) + lane * 8);
    }
  }

  float alpha = 1.f, beta = 0.f;
  if (!FIRST) {
    float sv = *skipv;
    alpha = 1.f / (1.f + __expf(-sv));
    beta = 1.f - alpha;
  }

  floatx4 acc1[8];
#pragma unroll
  for (int nt = 0; nt < 8; nt++) acc1[nt] = (floatx4){0.f, 0.f, 0.f, 0.f};
#pragma unroll
  for (int kc = 0; kc < 4; kc++) {
    half8v b[8];
#pragma unroll
    for (int nt = 0; nt < 8; nt++)
      b[nt] = *(const half8v*)(Wg1 + (size_t)nt * 2048 + (kc << 9) + lane * 8);
#pragma unroll
    for (int nt = 0; nt < 8; nt++)
      acc1[nt] = __builtin_amdgcn_mfma_f32_16x16x32_f16(a[kc], b[nt], acc1[nt], 0, 0, 0);
  }

  // epilogue1: per-64-col transpose; emit packed hbuf + LDS h-tile fragments
#pragma unroll
  for (int p = 0; p < 2; p++) {
    __syncthreads();
#pragma unroll
    for (int ntl = 0; ntl < 4; ntl++)
#pragma unroll
      for (int r = 0; r < 4; r++)
        myT[(q * 4 + r) * 68 + ntl * 16 + l16] = acc1[p * 4 + ntl][r];
    __syncthreads();
#pragma unroll
    for (int kc2 = 0; kc2 < 2; kc2++) {
      const float* rp = myT + mloc * 68 + kc2 * 32 + g * 8;
      floatx4 v0 = *(const floatx4*)rp;
      floatx4 v1 = *(const floatx4*)(rp + 4);
      float vals[8] = {v0[0], v0[1], v0[2], v0[3], v1[0], v1[1], v1[2], v1[3]};
      int col0 = p * 64 + kc2 * 32 + g * 8;
      size_t pbaseL = ((size_t)(tileC * 4 + (col0 >> 5)) << 9) + (size_t)lane * 8;
      if (FIRST) {
        float4 bb0 = *(const float4*)&bias[col0];
        float4 bb1 = *(const float4*)&bias[col0 + 4];
        float bbv[8] = {bb0.x, bb0.y, bb0.z, bb0.w, bb1.x, bb1.y, bb1.z, bb1.w};
#pragma unroll
        for (int j = 0; j < 8; j++) vals[j] = fmaxf(vals[j] + bbv[j], 0.f);
      } else {
        half8v hv = *(const half8v*)(hbuf + pbaseL);
#pragma unroll
        for (int j = 0; j < 8; j++)
          vals[j] = fmaxf(alpha * vals[j] + beta * (float)hv[j], 0.f);
      }
      half8v h8;
#pragma unroll
      for (int j = 0; j < 8; j++) h8[j] = (_Float16)vals[j];
      *(half8v*)(htile + (((p * 2 + kc2) << 9) + (g << 7) + (mloc << 3))) = h8;
      if (alive) *(half8v*)(hbuf + pbaseL) = h8;
    }
  }

  // GEMM2: kqv = h-tile @ Wcat (384 cols, 6 chunks of 64)
  for (int c = 0; c < 6; c++) {
    floatx4 acc2[4];
#pragma unroll
    for (int nt = 0; nt < 4; nt++) acc2[nt] = (floatx4){0.f, 0.f, 0.f, 0.f};
#pragma unroll
    for (int kc = 0; kc < 4; kc++) {
      half8v af = *(const half8v*)(htile + ((kc << 9) + lane * 8));
      half8v b[4];
#pragma unroll
      for (int nt = 0; nt < 4; nt++)
        b[nt] = *(const half8v*)(Wcat_l + (size_t)(c * 4 + nt) * 2048 + (kc << 9) + lane * 8);
#pragma unroll
      for (int nt = 0; nt < 4; nt++)
        acc2[nt] = __builtin_amdgcn_mfma_f32_16x16x32_f16(af, b[nt], acc2[nt], 0, 0, 0);
    }
    __syncthreads();
#pragma unroll
    for (int ntl = 0; ntl < 4; ntl++)
#pragma unroll
      for (int r = 0; r < 4; r++)
        myT[(q * 4 + r) * 68 + ntl * 16 + l16] = acc2[ntl][r];
    __syncthreads();
    if (alive) {
      int row = m0 + mloc;
#pragma unroll
      for (int kc2 = 0; kc2 < 2; kc2++) {
        const float* rp = myT + mloc * 68 + kc2 * 32 + g * 8;
        floatx4 v0 = *(const floatx4*)rp;
        floatx4 v1 = *(const floatx4*)(rp + 4);
        int col0 = c * 64 + kc2 * 32 + g * 8;
        int region = col0 >> 7;  // 0 kw, 1 q, 2 mv
        if (region == 1) {
          half8v h8;
#pragma unroll
          for (int j = 0; j < 4; j++) {
            h8[j] = (_Float16)v0[j];
            h8[j + 4] = (_Float16)v1[j];
          }
          *(half8v*)&qbuf[(size_t)row * 128 + (col0 - 128)] = h8;
        } else {
          int cc = col0 & 127;
          size_t base = (size_t)row * 256 + (size_t)(cc >> 2) * 8 + (region == 2 ? 4 : 0);
          half4v h0, h1;
#pragma unroll
          for (int j = 0; j < 4; j++) {
            h0[j] = (_Float16)v0[j];
            h1[j] = (_Float16)v1[j];
          }
          *(half4v*)&kwmv[base] = h0;
          *(half4v*)&kwmv[base + 8] = h1;
        }
      }
    }
  }
}

// ---------------- last Wa GEMM: hfinal = mix(agg @ Wa2, hold) (no relu) + hrow fp16
__global__ __launch_bounds__(256) void gemm_last(
    const _Float16* __restrict__ aggp, const _Float16* __restrict__ Wg1,
    const float* __restrict__ skipv, const _Float16* __restrict__ hbuf,
    float* __restrict__ hfinal, _Float16* __restrict__ hrow, int M) {
  int tid = threadIdx.x;
  int wave = tid >> 6, lane = tid & 63;
  int l16 = lane & 15, q = lane >> 4;
  int g = q, mloc = l16;
  int tile = blockIdx.x * 4 + wave;
  int m0 = tile * 16;
  bool alive = m0 < M;
  int tileC = alive ? tile : 0;

  __shared__ float ldsT_s[4][16 * 68];
  float* myT = ldsT_s[wave];

  half8v a[4];
#pragma unroll
  for (int kc = 0; kc < 4; kc++)
    a[kc] = *(const half8v*)(aggp + (size_t)tileC * 2048 + (kc << 9) + lane * 8);

  float sv = *skipv;
  float alpha = 1.f / (1.f + __expf(-sv));
  float beta = 1.f - alpha;

  floatx4 acc1[8];
#pragma unroll
  for (int nt = 0; nt < 8; nt++) acc1[nt] = (floatx4){0.f, 0.f, 0.f, 0.f};
#pragma unroll
  for (int kc = 0; kc < 4; kc++) {
    half8v b[8];
#pragma unroll
    for (int nt = 0; nt < 8; nt++)
      b[nt] = *(const half8v*)(Wg1 + (size_t)nt * 2048 + (kc << 9) + lane * 8);
#pragma unroll
    for (int nt = 0; nt < 8; nt++)
      acc1[nt] = __builtin_amdgcn_mfma_f32_16x16x32_f16(a[kc], b[nt], acc1[nt], 0, 0, 0);
  }

#pragma unroll
  for (int p = 0; p < 2; p++) {
    __syncthreads();
#pragma unroll
    for (int ntl = 0; ntl < 4; ntl++)
#pragma unroll
      for (int r = 0; r < 4; r++)
        myT[(q * 4 + r) * 68 + ntl * 16 + l16] = acc1[p * 4 + ntl][r];
    __syncthreads();
    if (alive) {
      int row = m0 + mloc;
#pragma unroll
      for (int kc2 = 0; kc2 < 2; kc2++) {
        const float* rp = myT + mloc * 68 + kc2 * 32 + g * 8;
        floatx4 v0 = *(const floatx4*)rp;
        floatx4 v1 = *(const floatx4*)(rp + 4);
        float vals[8] = {v0[0], v0[1], v0[2], v0[3], v1[0], v1[1], v1[2], v1[3]};
        int col0 = p * 64 + kc2 * 32 + g * 8;
        size_t pbase = ((size_t)(tile * 4 + (col0 >> 5)) << 9) + (size_t)lane * 8;
        half8v hv = *(const half8v*)(hbuf + pbase);
#pragma unroll
        for (int j = 0; j < 8; j++) vals[j] = alpha * vals[j] + beta * (float)hv[j];
        *(float4*)&hfinal[(size_t)row * 128 + col0] =
            make_float4(vals[0], vals[1], vals[2], vals[3]);
        *(float4*)&hfinal[(size_t)row * 128 + col0 + 4] =
            make_float4(vals[4], vals[5], vals[6], vals[7]);
        half8v h8;
#pragma unroll
        for (int j = 0; j < 8; j++) h8[j] = (_Float16)vals[j];
        *(half8v*)&hrow[(size_t)row * 128 + col0] = h8;
      }
    }
  }
}

// ---------------- fused predictor: Z=h[a]*h[b] -> W1+leaky -> W2+leaky -> dot W3
__global__ __launch_bounds__(256) void pred_fused(
    const _Float16* __restrict__ hrow,
    const int* __restrict__ ps, const int* __restrict__ pd,
    const int* __restrict__ ns, const int* __restrict__ nd,
    const _Float16* __restrict__ W1f, const float* __restrict__ b1,
    const _Float16* __restrict__ W2f, const float* __restrict__ b2,
    const float* __restrict__ W3, const float* __restrict__ b3,
    float* __restrict__ outd, int M) {
  int tid = threadIdx.x;
  int wave = tid >> 6, lane = tid & 63;
  int l16 = lane & 15, q = lane >> 4;
  int g = q, mloc = l16;
  int tile = blockIdx.x * 4 + wave;
  int m0 = tile * 16;
  bool alive = m0 < M;

  __shared__ _Float16 t1_s[4][1024];
  __shared__ float ldsT_s[4][16 * 68];
  _Float16* t1tile = t1_s[wave];
  float* myT = ldsT_s[wave];

  int gr = min(m0 + l16, M - 1);
  bool pos = gr < N_PAIRS;
  int idx = pos ? gr : gr - N_PAIRS;
  int pa = pos ? ps[idx] : ns[idx];
  int pb = pos ? pd[idx] : nd[idx];

  half8v a[4];
#pragma unroll
  for (int kc = 0; kc < 4; kc++) {
    int kbase = kc * 32 + q * 8;
    half8v ha = *(const half8v*)(hrow + (size_t)pa * 128 + kbase);
    half8v hb = *(const half8v*)(hrow + (size_t)pb * 128 + kbase);
    a[kc] = ha * hb;
  }

  floatx4 acc1[4];
#pragma unroll
  for (int nt = 0; nt < 4; nt++) acc1[nt] = (floatx4){0.f, 0.f, 0.f, 0.f};
#pragma unroll
  for (int kc = 0; kc < 4; kc++) {
    half8v b[4];
#pragma unroll
    for (int nt = 0; nt < 4; nt++)
      b[nt] = *(const half8v*)(W1f + (size_t)nt * 2048 + (kc << 9) + lane * 8);
#pragma unroll
    for (int nt = 0; nt < 4; nt++)
      acc1[nt] = __builtin_amdgcn_mfma_f32_16x16x32_f16(a[kc], b[nt], acc1[nt], 0, 0, 0);
  }

  // epilogue1: bias+leaky -> per-wave T1 fragments (16 rows x 64 k)
  __syncthreads();
#pragma unroll
  for (int ntl = 0; ntl < 4; ntl++)
#pragma unroll
    for (int r = 0; r < 4; r++)
      myT[(q * 4 + r) * 68 + ntl * 16 + l16] = acc1[ntl][r];
  __syncthreads();
#pragma unroll
  for (int kc2 = 0; kc2 < 2; kc2++) {
    const float* rp = myT + mloc * 68 + kc2 * 32 + g * 8;
    floatx4 v0 = *(const floatx4*)rp;
    floatx4 v1 = *(const floatx4*)(rp + 4);
    float vals[8] = {v0[0], v0[1], v0[2], v0[3], v1[0], v1[1], v1[2], v1[3]};
    int col0 = kc2 * 32 + g * 8;
    float4 bb0 = *(const float4*)&b1[col0];
    float4 bb1 = *(const float4*)&b1[col0 + 4];
    float bbv[8] = {bb0.x, bb0.y, bb0.z, bb0.w, bb1.x, bb1.y, bb1.z, bb1.w};
    half8v h8;
#pragma unroll
    for (int j = 0; j < 8; j++) {
      float v = vals[j] + bbv[j];
      v = v > 0.f ? v : 0.2f * v;
      h8[j] = (_Float16)v;
    }
    *(half8v*)(t1tile + ((kc2 << 9) + (g << 7) + (mloc << 3))) = h8;
  }

  // GEMM2: T1 @ W2 (K=64, N=32) + leaky + dot W3
  floatx4 acc2[2];
#pragma unroll
  for (int nt = 0; nt < 2; nt++) acc2[nt] = (floatx4){0.f, 0.f, 0.f, 0.f};
#pragma unroll
  for (int kc = 0; kc < 2; kc++) {
    half8v af = *(const half8v*)(t1tile + ((kc << 9) + lane * 8));
    half8v b[2];
#pragma unroll
    for (int nt = 0; nt < 2; nt++)
      b[nt] = *(const half8v*)(W2f + (size_t)nt * 1024 + (kc << 9) + lane * 8);
#pragma unroll
    for (int nt = 0; nt < 2; nt++)
      acc2[nt] = __builtin_amdgcn_mfma_f32_16x16x32_f16(af, b[nt], acc2[nt], 0, 0, 0);
  }

  float bw[2], wv[2];
#pragma unroll
  for (int nt = 0; nt < 2; nt++) {
    int col = nt * 16 + l16;
    bw[nt] = b2[col];
    wv[nt] = W3[col];
  }
  float b3v = b3[0];
#pragma unroll
  for (int r = 0; r < 4; r++) {
    float partial = 0.f;
#pragma unroll
    for (int nt = 0; nt < 2; nt++) {
      float v = acc2[nt][r] + bw[nt];
      v = v > 0.f ? v : 0.2f * v;
      partial += v * wv[nt];
    }
    partial += __shfl_xor(partial, 1);
    partial += __shfl_xor(partial, 2);
    partial += __shfl_xor(partial, 4);
    partial += __shfl_xor(partial, 8);
    int row = m0 + q * 4 + r;
    if (l16 == 0 && alive && row < M) outd[row] = partial + b3v;
  }
}

// ---------------- per-destination online-softmax aggregation
// one node per HALF-wave (32 lanes = one 512B kwmv row at 16B/lane):
// 2 independent gather chains per wave, 8-edge chunks (CSR padded to 8).
__global__ __launch_bounds__(256) void edge_agg_kernel(
    const _Float16* __restrict__ kwmv, const _Float16* __restrict__ qbuf,
    const int* __restrict__ poffs, const int2* __restrict__ eld,
    const int* __restrict__ perm,
    _Float16* __restrict__ agg, int n) {
  int hw = (blockIdx.x * 256 + threadIdx.x) >> 5;  // half-wave stream id
  int stride = gridDim.x << 3;                     // half-waves in grid
  int c4 = threadIdx.x & 31;
  int ch = c4 << 2;
  for (int gw = hw; gw < n; gw += stride) {
    int node = perm[gw];
    half4v qv = *(const half4v*)&qbuf[(size_t)node * 128 + ch];
    half2v q01 = {qv[0], qv[1]}, q23 = {qv[2], qv[3]};
    float m = -1e30f, s = 0.f;
    float a0 = 0.f, a1 = 0.f, a2 = 0.f, a3 = 0.f;
    int beg = poffs[node], end = poffs[node + 1];
    for (int j = beg; j < end; j += 8) {
      int2 e[8];
      half8v kvmv[8];
#pragma unroll
      for (int i = 0; i < 8; i++) {
        e[i] = eld[j + i];
        kvmv[i] = *(const half8v*)&kwmv[(size_t)max(e[i].x, 0) * 256 + (size_t)c4 * 8];
      }
      float p[8];
#pragma unroll
      for (int i = 0; i < 8; i++) {
        half2v k01 = {kvmv[i][0], kvmv[i][1]}, k23 = {kvmv[i][2], kvmv[i][3]};
        float d = __builtin_amdgcn_fdot2(
            k01, q01, __builtin_amdgcn_fdot2(k23, q23, 0.f, false), false);
        d += __shfl_xor(d, 1);
        d += __shfl_xor(d, 2);
        p[i] = (e[i].x >= 0) ? d : -1e30f;
      }
      float nm = m;
#pragma unroll
      for (int i = 0; i < 8; i++) nm = fmaxf(nm, p[i]);
      float sc = __expf(m - nm);
      float t[8];
      float ssum = 0.f;
#pragma unroll
      for (int i = 0; i < 8; i++) {
        t[i] = __expf(p[i] - nm);
        ssum += t[i];
      }
      s = s * sc + ssum;
      a0 *= sc; a1 *= sc; a2 *= sc; a3 *= sc;
#pragma unroll
      for (int i = 0; i < 8; i++) {
        float w = (e[i].x >= 0) ? __int_as_float(e[i].y) : 0.f;
        float f = t[i] * w;
        a0 += f * (float)kvmv[i][4];
        a1 += f * (float)kvmv[i][5];
        a2 += f * (float)kvmv[i][6];
        a3 += f * (float)kvmv[i][7];
      }
      m = nm;
    }
    float inv = (s > 0.f) ? 1.f / s : 0.f;
    half4v out4;
    out4[0] = (_Float16)(a0 * inv);
    out4[1] = (_Float16)(a1 * inv);
    out4[2] = (_Float16)(a2 * inv);
    out4[3] = (_Float16)(a3 * inv);
    *(half4v*)&agg[packA(node, ch, 128)] = out4;
  }
}

extern "C" void kernel_launch(void* const* d_in, const int* in_sizes, int n_in,
                              void* d_out, int out_size, void* d_ws, size_t ws_size,
                              hipStream_t stream) {
  const float* x        = (const float*)d_in[0];
  const int*   edge_src = (const int*)d_in[1];
  const int*   edge_dst = (const int*)d_in[2];
  const float* edge_w   = (const float*)d_in[3];
  const int*   pos_src  = (const int*)d_in[4];
  const int*   pos_dst  = (const int*)d_in[5];
  const int*   neg_src  = (const int*)d_in[6];
  const int*   neg_dst  = (const int*)d_in[7];
  const float* W_in     = (const float*)d_in[8];
  const float* b_in     = (const float*)d_in[9];
  const float* Wk       = (const float*)d_in[10];
  const float* Wq       = (const float*)d_in[11];
  const float* Wv       = (const float*)d_in[12];
  const float* att_w    = (const float*)d_in[13];
  const float* msg_w    = (const float*)d_in[14];
  const float* pri      = (const float*)d_in[15];
  const float* Wa       = (const float*)d_in[16];
  const float* skip     = (const float*)d_in[17];
  const float* W1       = (const float*)d_in[18];
  const float* b1       = (const float*)d_in[19];
  const float* W2       = (const float*)d_in[20];
  const float* b2       = (const float*)d_in[21];
  const float* W3       = (const float*)d_in[22];
  const float* b3       = (const float*)d_in[23];
  float* out = (float*)d_out;

  // ---- workspace layout (bytes), ~91 MB
  char* W = (char*)d_ws;
  _Float16*  qbuf   = (_Float16*)(W + 0);          // 12,800,000
  _Float16*  kwmv   = (_Float16*)(W + 12800000);   // 25,600,000
  _Float16*  hbuf   = (_Float16*)(W + 38400000);   // 12,800,000 (packed h)
  _Float16*  agg    = (_Float16*)(W + 51200000);   // 12,800,000
  _Float16*  Wint   = (_Float16*)(W + 64000000);   // 32,768
  _Float16*  Wcat   = (_Float16*)(W + 64032768);   // 294,912
  _Float16*  Waf    = (_Float16*)(W + 64327680);   // 98,304
  _Float16*  W1f    = (_Float16*)(W + 64425984);   // 16,384
  _Float16*  W2f    = (_Float16*)(W + 64442368);   // 8,192
  int2*      eld    = (int2*)(W + 64450560);       // 12,800,000 (padded-8 edges)
  int*       deg    = (int*)(W + 77250560);        // 200,000
  int*       poffs  = (int*)(W + 77450560);        // 200,016
  int*       cursor = (int*)(W + 77650576);        // 200,000
  int*       perm   = (int*)(W + 77850576);        // 200,000
  int*       bsum   = (int*)(W + 78050576);        // 1,024
  int*       boff   = (int*)(W + 78051600);        // 1,024
  int*       bh     = (int*)(W + 78052624);        // 1,024
  int*       bcur   = (int*)(W + 78053648);        // 1,024
  _Float16*  hrow   = (_Float16*)(W + 78054912);   // 12,800,000 (fp16 row-major hfinal)
  float* hfinal = out + 2 * N_PAIRS;

  hipMemsetAsync(deg, 0, N_NODES * sizeof(int), stream);
  hipMemsetAsync(bh, 0, 1024, stream);
  // sentinel: src=-1. pad-8 worst case: E + 7*N slots = 9.2MB
  hipMemsetAsync(eld, 0xFF, 9600000, stream);

  wprep_kernel<<<880, 256, 0, stream>>>(W_in, Wk, Wq, Wv, att_w, msg_w, pri, Wa, W1, W2,
                                        Wint, Wcat, Waf, W1f, W2f);
  hist_kernel<<<(N_EDGES + 255) / 256, 256, 0, stream>>>(edge_dst, deg, N_EDGES);
  scanA_kernel<<<196, 256, 0, stream>>>(deg, poffs, bsum, N_NODES);
  scanB_kernel<<<1, 256, 0, stream>>>(bsum, boff, poffs, 196, N_NODES);
  scanC_kernel<<<196, 256, 0, stream>>>(poffs, boff, cursor, N_NODES);
  scatter_kernel<<<(N_EDGES + 255) / 256, 256, 0, stream>>>(
      edge_src, edge_dst, edge_w, cursor, eld, N_EDGES);
  bhist_kernel<<<196, 256, 0, stream>>>(deg, bh, N_NODES);
  bscan_kernel<<<1, 256, 0, stream>>>(bh, bcur);
  bscatter_kernel<<<196, 256, 0, stream>>>(deg, bcur, perm, N_NODES);

  // layer 0: x -> h_in (relu proj) -> kqv0
  fused_layer<1><<<782, 256, 0, stream>>>(x, nullptr, Wint, b_in, nullptr, hbuf,
                                          Wcat, kwmv, qbuf, N_NODES);
  edge_agg_kernel<<<2048, 256, 0, stream>>>(kwmv, qbuf, poffs, eld, perm, agg, N_NODES);
  // layer 1: agg0 -> h0 (skip-mix+relu) -> kqv1
  fused_layer<0><<<782, 256, 0, stream>>>(nullptr, agg, Waf, nullptr, skip + 0, hbuf,
                                          Wcat + 49152, kwmv, qbuf, N_NODES);
  edge_agg_kernel<<<2048, 256, 0, stream>>>(kwmv, qbuf, poffs, eld, perm, agg, N_NODES);
  // layer 2: agg1 -> h1 (skip-mix+relu) -> kqv2
  fused_layer<0><<<782, 256, 0, stream>>>(nullptr, agg, Waf + 16384, nullptr, skip + 1,
                                          hbuf, Wcat + 98304, kwmv, qbuf, N_NODES);
  edge_agg_kernel<<<2048, 256, 0, stream>>>(kwmv, qbuf, poffs, eld, perm, agg, N_NODES);
  // final: agg2 -> hfinal (skip-mix, no relu) + hrow fp16
  gemm_last<<<782, 256, 0, stream>>>(agg, Waf + 32768, skip + 2, hbuf,
                                     hfinal, hrow, N_NODES);
  // predictor (fully fused)
  pred_fused<<<3125, 256, 0, stream>>>(hrow, pos_src, pos_dst, neg_src, neg_dst,
                                       W1f, b1, W2f, b2, W3, b3, out, 2 * N_PAIRS);
}

// Round 2
// 555.229 us; speedup vs baseline: 1.0067x; 1.0067x over previous
//
#include <hip/hip_runtime.h>
#include <cstddef>

#define N_NODES 50000
#define N_EDGES 800000
#define N_PAIRS 100000

typedef float floatx4 __attribute__((ext_vector_type(4)));
typedef _Float16 half2v __attribute__((ext_vector_type(2)));
typedef _Float16 half4v __attribute__((ext_vector_type(4)));
typedef _Float16 half8v __attribute__((ext_vector_type(8)));

// packed MFMA A/B-fragment layout: [tile16][kchunk32][lane][8] (fp16)
__device__ inline size_t packA(int m, int k, int K) {
  return ((size_t)((m >> 4) * (K >> 5) + (k >> 5)) << 9) +
         ((((unsigned)k >> 3) & 3) << 7) + ((m & 15) << 3) + (k & 7);
}

// ---------------- weight prep (fold + transpose + pack, fp16)
__device__ inline float fold_val(int l, int r, int j, const float* Wk, const float* Wq,
                                 const float* Wv, const float* att, const float* msg,
                                 const float* pri) {
  if (j >= 128 && j < 256) return Wq[(l * 128 + r) * 128 + (j - 128)];
  int jj = j & 127, hh = jj >> 4, e = jj & 15;
  const float* W = (j < 128) ? Wk : Wv;
  const float* T = (j < 128) ? att : msg;
  float s = 0.f;
#pragma unroll
  for (int d = 0; d < 16; d++)
    s += W[(l * 128 + r) * 128 + hh * 16 + d] * T[((l * 8 + hh) * 16 + d) * 16 + e];
  if (j < 128) s *= pri[l * 8 + hh] * 0.25f;
  return s;
}

__global__ void wprep_kernel(const float* __restrict__ W_in, const float* __restrict__ Wk,
                             const float* __restrict__ Wq, const float* __restrict__ Wv,
                             const float* __restrict__ att, const float* __restrict__ msg,
                             const float* __restrict__ pri, const float* __restrict__ Wa,
                             const float* __restrict__ W1, const float* __restrict__ W2,
                             _Float16* Wint, _Float16* Wcat, _Float16* Waf,
                             _Float16* W1f, _Float16* W2f) {
  int gid = blockIdx.x * 256 + threadIdx.x;
  float v;
  _Float16* dt;
  size_t o;
  if (gid < 16384) {
    int n = gid >> 7, k = gid & 127;
    v = W_in[k * 128 + n];
    dt = Wint; o = packA(n, k, 128);
  } else if (gid < 163840) {
    int t = gid - 16384;
    int l = t / 49152, u = t - l * 49152;
    int n = u >> 7, k = u & 127;
    v = fold_val(l, k, n, Wk, Wq, Wv, att, msg, pri);
    dt = Wcat + (size_t)l * 49152;
    o = packA(n, k, 128);
  } else if (gid < 212992) {
    int t = gid - 163840;
    int l = t / 16384, u = t & 16383;
    int n = u >> 7, k = u & 127;
    v = Wa[(size_t)l * 16384 + k * 128 + n];
    dt = Waf + (size_t)l * 16384;
    o = packA(n, k, 128);
  } else if (gid < 221184) {
    int u = gid - 212992;
    int n = u >> 7, k = u & 127;
    v = W1[k * 64 + n];
    dt = W1f; o = packA(n, k, 128);
  } else if (gid < 225280) {
    int u = gid - 221184;
    int n = u >> 6, k = u & 63;
    v = (n < 32) ? W2[k * 32 + n] : 0.f;
    dt = W2f; o = packA(n, k, 64);
  } else {
    return;
  }
  dt[o] = (_Float16)v;
}

// ---------------- CSR build (padded to multiple of 8 per node)
__global__ void hist_kernel(const int* __restrict__ dst, int* __restrict__ deg, int E) {
  int g = blockIdx.x * blockDim.x + threadIdx.x;
  if (g < E) atomicAdd(&deg[dst[g]], 1);
}

__global__ void scanA_kernel(const int* __restrict__ deg, int* __restrict__ offs,
                             int* __restrict__ bsum, int n) {
  __shared__ int sm[256];
  int t = threadIdx.x;
  int i = blockIdx.x * 256 + t;
  // pad each node's slot count to a multiple of 8 (half-wave chunk granularity)
  int v = (i < n) ? ((deg[i] + 7) & ~7) : 0;
  sm[t] = v;
  __syncthreads();
  for (int off = 1; off < 256; off <<= 1) {
    int u = (t >= off) ? sm[t - off] : 0;
    __syncthreads();
    sm[t] += u;
    __syncthreads();
  }
  if (i < n) offs[i] = sm[t] - v;
  if (t == 255) bsum[blockIdx.x] = sm[255];
}

__global__ void scanB_kernel(const int* __restrict__ bsum, int* __restrict__ boff,
                             int* __restrict__ offs, int nb, int n) {
  __shared__ int sm[256];
  int t = threadIdx.x;
  int v = (t < nb) ? bsum[t] : 0;
  sm[t] = v;
  __syncthreads();
  for (int off = 1; off < 256; off <<= 1) {
    int u = (t >= off) ? sm[t - off] : 0;
    __syncthreads();
    sm[t] += u;
    __syncthreads();
  }
  boff[t] = sm[t] - v;
  if (t == nb - 1) offs[n] = sm[t];
}

__global__ void scanC_kernel(int* __restrict__ offs, const int* __restrict__ boff,
                             int* __restrict__ cursor, int n) {
  int i = blockIdx.x * 256 + threadIdx.x;
  if (i < n) {
    int o = offs[i] + boff[blockIdx.x];
    offs[i] = o;
    cursor[i] = o;
  }
}

__global__ void scatter_kernel(const int* __restrict__ src, const int* __restrict__ dst,
                               const float* __restrict__ w, int* __restrict__ cursor,
                               int2* __restrict__ eld, int E) {
  int g = blockIdx.x * blockDim.x + threadIdx.x;
  if (g < E) {
    int d = dst[g];
    int p = atomicAdd(&cursor[d], 1);
    eld[p] = make_int2(src[g], __float_as_int(w[g]));
  }
}

// ---------------- degree-descending node permutation (counting sort, 256 buckets)
__global__ void bhist_kernel(const int* __restrict__ deg, int* __restrict__ bh, int n) {
  __shared__ int lh[256];
  int t = threadIdx.x;
  lh[t] = 0;
  __syncthreads();
  int i = blockIdx.x * 256 + t;
  if (i < n) atomicAdd(&lh[min(deg[i], 255)], 1);
  __syncthreads();
  if (lh[t]) atomicAdd(&bh[t], lh[t]);
}
__global__ void bscan_kernel(const int* __restrict__ bh, int* __restrict__ bcur) {
  __shared__ int sm[256];
  int t = threadIdx.x;
  int v = bh[255 - t];
  sm[t] = v;
  __syncthreads();
  for (int off = 1; off < 256; off <<= 1) {
    int u = (t >= off) ? sm[t - off] : 0;
    __syncthreads();
    sm[t] += u;
    __syncthreads();
  }
  bcur[255 - t] = sm[t] - v;
}
__global__ void bscatter_kernel(const int* __restrict__ deg, int* __restrict__ bcur,
                                int* __restrict__ perm, int n) {
  __shared__ int lh[256], lbase[256];
  int t = threadIdx.x;
  lh[t] = 0;
  __syncthreads();
  int i = blockIdx.x * 256 + t;
  int b = 0, local = 0;
  if (i < n) {
    b = min(deg[i], 255);
    local = atomicAdd(&lh[b], 1);
  }
  __syncthreads();
  int cnt = lh[t];
  lbase[t] = cnt ? atomicAdd(&bcur[t], cnt) : 0;
  __syncthreads();
  if (i < n) perm[lbase[b] + local] = i;
}

// ---------------- fused layer kernel: GEMM1 (h) -> LDS fragments -> GEMM2 (kqv)
// FIRST=1: h = relu(x @ Wg1 + bias); FIRST=0: h = mix(agg @ Wg1, hold=hbuf) + relu
// then kqv = h @ Wcat -> kwmv/qbuf; h also written packed to hbuf (next layer's hold)
template <int FIRST>
__global__ __launch_bounds__(256) void fused_layer(
    const float* __restrict__ x, const _Float16* __restrict__ aggp,
    const _Float16* __restrict__ Wg1, const float* __restrict__ bias,
    const float* __restrict__ skipv, _Float16* __restrict__ hbuf,
    const _Float16* __restrict__ Wcat_l,
    _Float16* __restrict__ kwmv, _Float16* __restrict__ qbuf, int M) {
  int tid = threadIdx.x;
  int wave = tid >> 6, lane = tid & 63;
  int l16 = lane & 15, q = lane >> 4;
  int g = q, mloc = l16;
  int tile = blockIdx.x * 4 + wave;
  int m0 = tile * 16;
  bool alive = m0 < M;
  int tileC = alive ? tile : 0;

  __shared__ _Float16 htile_s[4][2048];
  __shared__ float ldsT_s[4][16 * 68];
  _Float16* htile = htile_s[wave];
  float* myT = ldsT_s[wave];

  // GEMM1 A fragments
  half8v a[4];
#pragma unroll
  for (int kc = 0; kc < 4; kc++) {
    if (FIRST) {
      int row = min(m0 + l16, M - 1);
      const float* p = x + (size_t)row * 128 + kc * 32 + q * 8;
      float4 u0 = *(const float4*)p, u1 = *(const float4*)(p + 4);
      float f[8] = {u0.x, u0.y, u0.z, u0.w, u1.x, u1.y, u1.z, u1.w};
      half8v hv;
#pragma unroll
      for (int i = 0; i < 8; i++) hv[i] = (_Float16)f[i];
      a[kc] = hv;
    } else {
      a[kc] = *(const half8v*)(aggp + (size_t)tileC * 2048 + (kc << 9) + lane * 8);
    }
  }

  float alpha = 1.f, beta = 0.f;
  if (!FIRST) {
    float sv = *skipv;
    alpha = 1.f / (1.f + __expf(-sv));
    beta = 1.f - alpha;
  }

  floatx4 acc1[8];
#pragma unroll
  for (int nt = 0; nt < 8; nt++) acc1[nt] = (floatx4){0.f, 0.f, 0.f, 0.f};
#pragma unroll
  for (int kc = 0; kc < 4; kc++) {
    half8v b[8];
#pragma unroll
    for (int nt = 0; nt < 8; nt++)
      b[nt] = *(const half8v*)(Wg1 + (size_t)nt * 2048 + (kc << 9) + lane * 8);
#pragma unroll
    for (int nt = 0; nt < 8; nt++)
      acc1[nt] = __builtin_amdgcn_mfma_f32_16x16x32_f16(a[kc], b[nt], acc1[nt], 0, 0, 0);
  }

  // epilogue1: per-64-col transpose; emit packed hbuf + LDS h-tile fragments
#pragma unroll
  for (int p = 0; p < 2; p++) {
    __syncthreads();
#pragma unroll
    for (int ntl = 0; ntl < 4; ntl++)
#pragma unroll
      for (int r = 0; r < 4; r++)
        myT[(q * 4 + r) * 68 + ntl * 16 + l16] = acc1[p * 4 + ntl][r];
    __syncthreads();
#pragma unroll
    for (int kc2 = 0; kc2 < 2; kc2++) {
      const float* rp = myT + mloc * 68 + kc2 * 32 + g * 8;
      floatx4 v0 = *(const floatx4*)rp;
      floatx4 v1 = *(const floatx4*)(rp + 4);
      float vals[8] = {v0[0], v0[1], v0[2], v0[3], v1[0], v1[1], v1[2], v1[3]};
      int col0 = p * 64 + kc2 * 32 + g * 8;
      size_t pbaseL = ((size_t)(tileC * 4 + (col0 >> 5)) << 9) + (size_t)lane * 8;
      if (FIRST) {
        float4 bb0 = *(const float4*)&bias[col0];
        float4 bb1 = *(const float4*)&bias[col0 + 4];
        float bbv[8] = {bb0.x, bb0.y, bb0.z, bb0.w, bb1.x, bb1.y, bb1.z, bb1.w};
#pragma unroll
        for (int j = 0; j < 8; j++) vals[j] = fmaxf(vals[j] + bbv[j], 0.f);
      } else {
        half8v hv = *(const half8v*)(hbuf + pbaseL);
#pragma unroll
        for (int j = 0; j < 8; j++)
          vals[j] = fmaxf(alpha * vals[j] + beta * (float)hv[j], 0.f);
      }
      half8v h8;
#pragma unroll
      for (int j = 0; j < 8; j++) h8[j] = (_Float16)vals[j];
      *(half8v*)(htile + (((p * 2 + kc2) << 9) + (g << 7) + (mloc << 3))) = h8;
      if (alive) *(half8v*)(hbuf + pbaseL) = h8;
    }
  }

  // GEMM2: kqv = h-tile @ Wcat (384 cols, 6 chunks of 64)
  for (int c = 0; c < 6; c++) {
    floatx4 acc2[4];
#pragma unroll
    for (int nt = 0; nt < 4; nt++) acc2[nt] = (floatx4){0.f, 0.f, 0.f, 0.f};
#pragma unroll
    for (int kc = 0; kc < 4; kc++) {
      half8v af = *(const half8v*)(htile + ((kc << 9) + lane * 8));
      half8v b[4];
#pragma unroll
      for (int nt = 0; nt < 4; nt++)
        b[nt] = *(const half8v*)(Wcat_l + (size_t)(c * 4 + nt) * 2048 + (kc << 9) + lane * 8);
#pragma unroll
      for (int nt = 0; nt < 4; nt++)
        acc2[nt] = __builtin_amdgcn_mfma_f32_16x16x32_f16(af, b[nt], acc2[nt], 0, 0, 0);
    }
    __syncthreads();
#pragma unroll
    for (int ntl = 0; ntl < 4; ntl++)
#pragma unroll
      for (int r = 0; r < 4; r++)
        myT[(q * 4 + r) * 68 + ntl * 16 + l16] = acc2[ntl][r];
    __syncthreads();
    if (alive) {
      int row = m0 + mloc;
#pragma unroll
      for (int kc2 = 0; kc2 < 2; kc2++) {
        const float* rp = myT + mloc * 68 + kc2 * 32 + g * 8;
        floatx4 v0 = *(const floatx4*)rp;
        floatx4 v1 = *(const floatx4*)(rp + 4);
        int col0 = c * 64 + kc2 * 32 + g * 8;
        int region = col0 >> 7;  // 0 kw, 1 q, 2 mv
        if (region == 1) {
          half8v h8;
#pragma unroll
          for (int j = 0; j < 4; j++) {
            h8[j] = (_Float16)v0[j];
            h8[j + 4] = (_Float16)v1[j];
          }
          *(half8v*)&qbuf[(size_t)row * 128 + (col0 - 128)] = h8;
        } else {
          int cc = col0 & 127;
          size_t base = (size_t)row * 256 + (size_t)(cc >> 2) * 8 + (region == 2 ? 4 : 0);
          half4v h0, h1;
#pragma unroll
          for (int j = 0; j < 4; j++) {
            h0[j] = (_Float16)v0[j];
            h1[j] = (_Float16)v1[j];
          }
          *(half4v*)&kwmv[base] = h0;
          *(half4v*)&kwmv[base + 8] = h1;
        }
      }
    }
  }
}

// ---------------- last Wa GEMM: hfinal = mix(agg @ Wa2, hold) (no relu) + hrow fp16
__global__ __launch_bounds__(256) void gemm_last(
    const _Float16* __restrict__ aggp, const _Float16* __restrict__ Wg1,
    const float* __restrict__ skipv, const _Float16* __restrict__ hbuf,
    float* __restrict__ hfinal, _Float16* __restrict__ hrow, int M) {
  int tid = threadIdx.x;
  int wave = tid >> 6, lane = tid & 63;
  int l16 = lane & 15, q = lane >> 4;
  int g = q, mloc = l16;
  int tile = blockIdx.x * 4 + wave;
  int m0 = tile * 16;
  bool alive = m0 < M;
  int tileC = alive ? tile : 0;

  __shared__ float ldsT_s[4][16 * 68];
  float* myT = ldsT_s[wave];

  half8v a[4];
#pragma unroll
  for (int kc = 0; kc < 4; kc++)
    a[kc] = *(const half8v*)(aggp + (size_t)tileC * 2048 + (kc << 9) + lane * 8);

  float sv = *skipv;
  float alpha = 1.f / (1.f + __expf(-sv));
  float beta = 1.f - alpha;

  floatx4 acc1[8];
#pragma unroll
  for (int nt = 0; nt < 8; nt++) acc1[nt] = (floatx4){0.f, 0.f, 0.f, 0.f};
#pragma unroll
  for (int kc = 0; kc < 4; kc++) {
    half8v b[8];
#pragma unroll
    for (int nt = 0; nt < 8; nt++)
      b[nt] = *(const half8v*)(Wg1 + (size_t)nt * 2048 + (kc << 9) + lane * 8);
#pragma unroll
    for (int nt = 0; nt < 8; nt++)
      acc1[nt] = __builtin_amdgcn_mfma_f32_16x16x32_f16(a[kc], b[nt], acc1[nt], 0, 0, 0);
  }

#pragma unroll
  for (int p = 0; p < 2; p++) {
    __syncthreads();
#pragma unroll
    for (int ntl = 0; ntl < 4; ntl++)
#pragma unroll
      for (int r = 0; r < 4; r++)
        myT[(q * 4 + r) * 68 + ntl * 16 + l16] = acc1[p * 4 + ntl][r];
    __syncthreads();
    if (alive) {
      int row = m0 + mloc;
#pragma unroll
      for (int kc2 = 0; kc2 < 2; kc2++) {
        const float* rp = myT + mloc * 68 + kc2 * 32 + g * 8;
        floatx4 v0 = *(const floatx4*)rp;
        floatx4 v1 = *(const floatx4*)(rp + 4);
        float vals[8] = {v0[0], v0[1], v0[2], v0[3], v1[0], v1[1], v1[2], v1[3]};
        int col0 = p * 64 + kc2 * 32 + g * 8;
        size_t pbase = ((size_t)(tile * 4 + (col0 >> 5)) << 9) + (size_t)lane * 8;
        half8v hv = *(const half8v*)(hbuf + pbase);
#pragma unroll
        for (int j = 0; j < 8; j++) vals[j] = alpha * vals[j] + beta * (float)hv[j];
        *(float4*)&hfinal[(size_t)row * 128 + col0] =
            make_float4(vals[0], vals[1], vals[2], vals[3]);
        *(float4*)&hfinal[(size_t)row * 128 + col0 + 4] =
            make_float4(vals[4], vals[5], vals[6], vals[7]);
        half8v h8;
#pragma unroll
        for (int j = 0; j < 8; j++) h8[j] = (_Float16)vals[j];
        *(half8v*)&hrow[(size_t)row * 128 + col0] = h8;
      }
    }
  }
}

// ---------------- fused predictor: Z=h[a]*h[b] -> W1+leaky -> W2+leaky -> dot W3
__global__ __launch_bounds__(256) void pred_fused(
    const _Float16* __restrict__ hrow,
    const int* __restrict__ ps, const int* __restrict__ pd,
    const int* __restrict__ ns, const int* __restrict__ nd,
    const _Float16* __restrict__ W1f, const float* __restrict__ b1,
    const _Float16* __restrict__ W2f, const float* __restrict__ b2,
    const float* __restrict__ W3, const float* __restrict__ b3,
    float* __restrict__ outd, int M) {
  int tid = threadIdx.x;
  int wave = tid >> 6, lane = tid & 63;
  int l16 = lane & 15, q = lane >> 4;
  int g = q, mloc = l16;
  int tile = blockIdx.x * 4 + wave;
  int m0 = tile * 16;
  bool alive = m0 < M;

  __shared__ _Float16 t1_s[4][1024];
  __shared__ float ldsT_s[4][16 * 68];
  _Float16* t1tile = t1_s[wave];
  float* myT = ldsT_s[wave];

  int gr = min(m0 + l16, M - 1);
  bool pos = gr < N_PAIRS;
  int idx = pos ? gr : gr - N_PAIRS;
  int pa = pos ? ps[idx] : ns[idx];
  int pb = pos ? pd[idx] : nd[idx];

  half8v a[4];
#pragma unroll
  for (int kc = 0; kc < 4; kc++) {
    int kbase = kc * 32 + q * 8;
    half8v ha = *(const half8v*)(hrow + (size_t)pa * 128 + kbase);
    half8v hb = *(const half8v*)(hrow + (size_t)pb * 128 + kbase);
    a[kc] = ha * hb;
  }

  floatx4 acc1[4];
#pragma unroll
  for (int nt = 0; nt < 4; nt++) acc1[nt] = (floatx4){0.f, 0.f, 0.f, 0.f};
#pragma unroll
  for (int kc = 0; kc < 4; kc++) {
    half8v b[4];
#pragma unroll
    for (int nt = 0; nt < 4; nt++)
      b[nt] = *(const half8v*)(W1f + (size_t)nt * 2048 + (kc << 9) + lane * 8);
#pragma unroll
    for (int nt = 0; nt < 4; nt++)
      acc1[nt] = __builtin_amdgcn_mfma_f32_16x16x32_f16(a[kc], b[nt], acc1[nt], 0, 0, 0);
  }

  // epilogue1: bias+leaky -> per-wave T1 fragments (16 rows x 64 k)
  __syncthreads();
#pragma unroll
  for (int ntl = 0; ntl < 4; ntl++)
#pragma unroll
    for (int r = 0; r < 4; r++)
      myT[(q * 4 + r) * 68 + ntl * 16 + l16] = acc1[ntl][r];
  __syncthreads();
#pragma unroll
  for (int kc2 = 0; kc2 < 2; kc2++) {
    const float* rp = myT + mloc * 68 + kc2 * 32 + g * 8;
    floatx4 v0 = *(const floatx4*)rp;
    floatx4 v1 = *(const floatx4*)(rp + 4);
    float vals[8] = {v0[0], v0[1], v0[2], v0[3], v1[0], v1[1], v1[2], v1[3]};
    int col0 = kc2 * 32 + g * 8;
    float4 bb0 = *(const float4*)&b1[col0];
    float4 bb1 = *(const float4*)&b1[col0 + 4];
    float bbv[8] = {bb0.x, bb0.y, bb0.z, bb0.w, bb1.x, bb1.y, bb1.z, bb1.w};
    half8v h8;
#pragma unroll
    for (int j = 0; j < 8; j++) {
      float v = vals[j] + bbv[j];
      v = v > 0.f ? v : 0.2f * v;
      h8[j] = (_Float16)v;
    }
    *(half8v*)(t1tile + ((kc2 << 9) + (g << 7) + (mloc << 3))) = h8;
  }

  // GEMM2: T1 @ W2 (K=64, N=32) + leaky + dot W3
  floatx4 acc2[2];
#pragma unroll
  for (int nt = 0; nt < 2; nt++) acc2[nt] = (floatx4){0.f, 0.f, 0.f, 0.f};
#pragma unroll
  for (int kc = 0; kc < 2; kc++) {
    half8v af = *(const half8v*)(t1tile + ((kc << 9) + lane * 8));
    half8v b[2];
#pragma unroll
    for (int nt = 0; nt < 2; nt++)
      b[nt] = *(const half8v*)(W2f + (size_t)nt * 1024 + (kc << 9) + lane * 8);
#pragma unroll
    for (int nt = 0; nt < 2; nt++)
      acc2[nt] = __builtin_amdgcn_mfma_f32_16x16x32_f16(af, b[nt], acc2[nt], 0, 0, 0);
  }

  float bw[2], wv[2];
#pragma unroll
  for (int nt = 0; nt < 2; nt++) {
    int col = nt * 16 + l16;
    bw[nt] = b2[col];
    wv[nt] = W3[col];
  }
  float b3v = b3[0];
#pragma unroll
  for (int r = 0; r < 4; r++) {
    float partial = 0.f;
#pragma unroll
    for (int nt = 0; nt < 2; nt++) {
      float v = acc2[nt][r] + bw[nt];
      v = v > 0.f ? v : 0.2f * v;
      partial += v * wv[nt];
    }
    partial += __shfl_xor(partial, 1);
    partial += __shfl_xor(partial, 2);
    partial += __shfl_xor(partial, 4);
    partial += __shfl_xor(partial, 8);
    int row = m0 + q * 4 + r;
    if (l16 == 0 && alive && row < M) outd[row] = partial + b3v;
  }
}

// ---------------- per-destination online-softmax aggregation
// one node per HALF-wave; depth-3 software pipeline:
//   E[j] consumed by compute, E[j+1] arrived -> issue G[j+1], E[j+2] in flight.
// keeps one 4KB gather set in flight during every compute phase (latency hiding).
__global__ __launch_bounds__(256) void edge_agg_kernel(
    const _Float16* __restrict__ kwmv, const _Float16* __restrict__ qbuf,
    const int* __restrict__ poffs, const int2* __restrict__ eld,
    const int* __restrict__ perm,
    _Float16* __restrict__ agg, int n) {
  int hw = (blockIdx.x * 256 + threadIdx.x) >> 5;  // half-wave stream id
  int stride = gridDim.x << 3;                     // half-waves in grid
  int c4 = threadIdx.x & 31;
  int ch = c4 << 2;
  for (int gw = hw; gw < n; gw += stride) {
    int node = perm[gw];
    half4v qv = *(const half4v*)&qbuf[(size_t)node * 128 + ch];
    half2v q01 = {qv[0], qv[1]}, q23 = {qv[2], qv[3]};
    float m = -1e30f, s = 0.f;
    float a0 = 0.f, a1 = 0.f, a2 = 0.f, a3 = 0.f;
    int beg = poffs[node], end = poffs[node + 1];
    if (beg < end) {
      int2 e0[8], e1[8], e2[8];
      half8v g0[8], g1[8];
      // prologue: load chunk0 meta, issue chunk0 gathers, prefetch chunk1 meta
#pragma unroll
      for (int i = 0; i < 8; i++) e0[i] = eld[beg + i];
#pragma unroll
      for (int i = 0; i < 8; i++)
        g0[i] = *(const half8v*)&kwmv[(size_t)max(e0[i].x, 0) * 256 + (size_t)c4 * 8];
#pragma unroll
      for (int i = 0; i < 8; i++) e1[i] = eld[beg + 8 + i];
      int j = beg;
      for (; j + 8 < end; j += 8) {
        // issue next chunk's gathers (waits only on e1 arrival; g0 stays in flight)
#pragma unroll
        for (int i = 0; i < 8; i++)
          g1[i] = *(const half8v*)&kwmv[(size_t)max(e1[i].x, 0) * 256 + (size_t)c4 * 8];
        // prefetch meta two chunks ahead (may read past `end`; region is allocated)
#pragma unroll
        for (int i = 0; i < 8; i++) e2[i] = eld[j + 16 + i];
        // ---- compute on (e0, g0) — overlaps g1 + e2 flight
        float p[8];
#pragma unroll
        for (int i = 0; i < 8; i++) {
          half2v k01 = {g0[i][0], g0[i][1]}, k23 = {g0[i][2], g0[i][3]};
          float d = __builtin_amdgcn_fdot2(
              k01, q01, __builtin_amdgcn_fdot2(k23, q23, 0.f, false), false);
          d += __shfl_xor(d, 1);
          d += __shfl_xor(d, 2);
          p[i] = (e0[i].x >= 0) ? d : -1e30f;
        }
        float nm = m;
#pragma unroll
        for (int i = 0; i < 8; i++) nm = fmaxf(nm, p[i]);
        float sc = __expf(m - nm);
        float t[8];
        float ssum = 0.f;
#pragma unroll
        for (int i = 0; i < 8; i++) {
          t[i] = __expf(p[i] - nm);
          ssum += t[i];
        }
        s = s * sc + ssum;
        a0 *= sc; a1 *= sc; a2 *= sc; a3 *= sc;
#pragma unroll
        for (int i = 0; i < 8; i++) {
          float w = (e0[i].x >= 0) ? __int_as_float(e0[i].y) : 0.f;
          float f = t[i] * w;
          a0 += f * (float)g0[i][4];
          a1 += f * (float)g0[i][5];
          a2 += f * (float)g0[i][6];
          a3 += f * (float)g0[i][7];
        }
        m = nm;
        // rotate pipeline registers (static indices; compiler renames)
#pragma unroll
        for (int i = 0; i < 8; i++) {
          e0[i] = e1[i];
          e1[i] = e2[i];
          g0[i] = g1[i];
        }
      }
      // epilogue: last chunk
      {
        float p[8];
#pragma unroll
        for (int i = 0; i < 8; i++) {
          half2v k01 = {g0[i][0], g0[i][1]}, k23 = {g0[i][2], g0[i][3]};
          float d = __builtin_amdgcn_fdot2(
              k01, q01, __builtin_amdgcn_fdot2(k23, q23, 0.f, false), false);
          d += __shfl_xor(d, 1);
          d += __shfl_xor(d, 2);
          p[i] = (e0[i].x >= 0) ? d : -1e30f;
        }
        float nm = m;
#pragma unroll
        for (int i = 0; i < 8; i++) nm = fmaxf(nm, p[i]);
        float sc = __expf(m - nm);
        float t[8];
        float ssum = 0.f;
#pragma unroll
        for (int i = 0; i < 8; i++) {
          t[i] = __expf(p[i] - nm);
          ssum += t[i];
        }
        s = s * sc + ssum;
        a0 *= sc; a1 *= sc; a2 *= sc; a3 *= sc;
#pragma unroll
        for (int i = 0; i < 8; i++) {
          float w = (e0[i].x >= 0) ? __int_as_float(e0[i].y) : 0.f;
          float f = t[i] * w;
          a0 += f * (float)g0[i][4];
          a1 += f * (float)g0[i][5];
          a2 += f * (float)g0[i][6];
          a3 += f * (float)g0[i][7];
        }
      }
    }
    float inv = (s > 0.f) ? 1.f / s : 0.f;
    half4v out4;
    out4[0] = (_Float16)(a0 * inv);
    out4[1] = (_Float16)(a1 * inv);
    out4[2] = (_Float16)(a2 * inv);
    out4[3] = (_Float16)(a3 * inv);
    *(half4v*)&agg[packA(node, ch, 128)] = out4;
  }
}

extern "C" void kernel_launch(void* const* d_in, const int* in_sizes, int n_in,
                              void* d_out, int out_size, void* d_ws, size_t ws_size,
                              hipStream_t stream) {
  const float* x        = (const float*)d_in[0];
  const int*   edge_src = (const int*)d_in[1];
  const int*   edge_dst = (const int*)d_in[2];
  const float* edge_w   = (const float*)d_in[3];
  const int*   pos_src  = (const int*)d_in[4];
  const int*   pos_dst  = (const int*)d_in[5];
  const int*   neg_src  = (const int*)d_in[6];
  const int*   neg_dst  = (const int*)d_in[7];
  const float* W_in     = (const float*)d_in[8];
  const float* b_in     = (const float*)d_in[9];
  const float* Wk       = (const float*)d_in[10];
  const float* Wq       = (const float*)d_in[11];
  const float* Wv       = (const float*)d_in[12];
  const float* att_w    = (const float*)d_in[13];
  const float* msg_w    = (const float*)d_in[14];
  const float* pri      = (const float*)d_in[15];
  const float* Wa       = (const float*)d_in[16];
  const float* skip     = (const float*)d_in[17];
  const float* W1       = (const float*)d_in[18];
  const float* b1       = (const float*)d_in[19];
  const float* W2       = (const float*)d_in[20];
  const float* b2       = (const float*)d_in[21];
  const float* W3       = (const float*)d_in[22];
  const float* b3       = (const float*)d_in[23];
  float* out = (float*)d_out;

  // ---- workspace layout (bytes), ~91 MB
  char* W = (char*)d_ws;
  _Float16*  qbuf   = (_Float16*)(W + 0);          // 12,800,000
  _Float16*  kwmv   = (_Float16*)(W + 12800000);   // 25,600,000
  _Float16*  hbuf   = (_Float16*)(W + 38400000);   // 12,800,000 (packed h)
  _Float16*  agg    = (_Float16*)(W + 51200000);   // 12,800,000
  _Float16*  Wint   = (_Float16*)(W + 64000000);   // 32,768
  _Float16*  Wcat   = (_Float16*)(W + 64032768);   // 294,912
  _Float16*  Waf    = (_Float16*)(W + 64327680);   // 98,304
  _Float16*  W1f    = (_Float16*)(W + 64425984);   // 16,384
  _Float16*  W2f    = (_Float16*)(W + 64442368);   // 8,192
  int2*      eld    = (int2*)(W + 64450560);       // 12,800,000 (padded-8 edges)
  int*       deg    = (int*)(W + 77250560);        // 200,000
  int*       poffs  = (int*)(W + 77450560);        // 200,016
  int*       cursor = (int*)(W + 77650576);        // 200,000
  int*       perm   = (int*)(W + 77850576);        // 200,000
  int*       bsum   = (int*)(W + 78050576);        // 1,024
  int*       boff   = (int*)(W + 78051600);        // 1,024
  int*       bh     = (int*)(W + 78052624);        // 1,024
  int*       bcur   = (int*)(W + 78053648);        // 1,024
  _Float16*  hrow   = (_Float16*)(W + 78054912);   // 12,800,000 (fp16 row-major hfinal)
  float* hfinal = out + 2 * N_PAIRS;

  hipMemsetAsync(deg, 0, N_NODES * sizeof(int), stream);
  hipMemsetAsync(bh, 0, 1024, stream);
  // sentinel: src=-1. pad-8 worst case: E + 7*N slots = 9.2MB
  hipMemsetAsync(eld, 0xFF, 9600000, stream);

  wprep_kernel<<<880, 256, 0, stream>>>(W_in, Wk, Wq, Wv, att_w, msg_w, pri, Wa, W1, W2,
                                        Wint, Wcat, Waf, W1f, W2f);
  hist_kernel<<<(N_EDGES + 255) / 256, 256, 0, stream>>>(edge_dst, deg, N_EDGES);
  scanA_kernel<<<196, 256, 0, stream>>>(deg, poffs, bsum, N_NODES);
  scanB_kernel<<<1, 256, 0, stream>>>(bsum, boff, poffs, 196, N_NODES);
  scanC_kernel<<<196, 256, 0, stream>>>(poffs, boff, cursor, N_NODES);
  scatter_kernel<<<(N_EDGES + 255) / 256, 256, 0, stream>>>(
      edge_src, edge_dst, edge_w, cursor, eld, N_EDGES);
  bhist_kernel<<<196, 256, 0, stream>>>(deg, bh, N_NODES);
  bscan_kernel<<<1, 256, 0, stream>>>(bh, bcur);
  bscatter_kernel<<<196, 256, 0, stream>>>(deg, bcur, perm, N_NODES);

  // layer 0: x -> h_in (relu proj) -> kqv0
  fused_layer<1><<<782, 256, 0, stream>>>(x, nullptr, Wint, b_in, nullptr, hbuf,
                                          Wcat, kwmv, qbuf, N_NODES);
  edge_agg_kernel<<<2048, 256, 0, stream>>>(kwmv, qbuf, poffs, eld, perm, agg, N_NODES);
  // layer 1: agg0 -> h0 (skip-mix+relu) -> kqv1
  fused_layer<0><<<782, 256, 0, stream>>>(nullptr, agg, Waf, nullptr, skip + 0, hbuf,
                                          Wcat + 49152, kwmv, qbuf, N_NODES);
  edge_agg_kernel<<<2048, 256, 0, stream>>>(kwmv, qbuf, poffs, eld, perm, agg, N_NODES);
  // layer 2: agg1 -> h1 (skip-mix+relu) -> kqv2
  fused_layer<0><<<782, 256, 0, stream>>>(nullptr, agg, Waf + 16384, nullptr, skip + 1,
                                          hbuf, Wcat + 98304, kwmv, qbuf, N_NODES);
  edge_agg_kernel<<<2048, 256, 0, stream>>>(kwmv, qbuf, poffs, eld, perm, agg, N_NODES);
  // final: agg2 -> hfinal (skip-mix, no relu) + hrow fp16
  gemm_last<<<782, 256, 0, stream>>>(agg, Waf + 32768, skip + 2, hbuf,
                                     hfinal, hrow, N_NODES);
  // predictor (fully fused)
  pred_fused<<<3125, 256, 0, stream>>>(hrow, pos_src, pos_dst, neg_src, neg_dst,
                                       W1f, b1, W2f, b2, W3, b3, out, 2 * N_PAIRS);
}

// Round 3
// 546.013 us; speedup vs baseline: 1.0237x; 1.0169x over previous
//
#include <hip/hip_runtime.h>
#include <cstddef>

#define N_NODES 50000
#define N_EDGES 800000
#define N_PAIRS 100000

typedef float floatx4 __attribute__((ext_vector_type(4)));
typedef _Float16 half2v __attribute__((ext_vector_type(2)));
typedef _Float16 half4v __attribute__((ext_vector_type(4)));
typedef _Float16 half8v __attribute__((ext_vector_type(8)));

// packed MFMA A/B-fragment layout: [tile16][kchunk32][lane][8] (fp16)
__device__ inline size_t packA(int m, int k, int K) {
  return ((size_t)((m >> 4) * (K >> 5) + (k >> 5)) << 9) +
         ((((unsigned)k >> 3) & 3) << 7) + ((m & 15) << 3) + (k & 7);
}

// ---------------- weight prep (fold + transpose + pack, fp16)
__device__ inline float fold_val(int l, int r, int j, const float* Wk, const float* Wq,
                                 const float* Wv, const float* att, const float* msg,
                                 const float* pri) {
  if (j >= 128 && j < 256) return Wq[(l * 128 + r) * 128 + (j - 128)];
  int jj = j & 127, hh = jj >> 4, e = jj & 15;
  const float* W = (j < 128) ? Wk : Wv;
  const float* T = (j < 128) ? att : msg;
  float s = 0.f;
#pragma unroll
  for (int d = 0; d < 16; d++)
    s += W[(l * 128 + r) * 128 + hh * 16 + d] * T[((l * 8 + hh) * 16 + d) * 16 + e];
  if (j < 128) s *= pri[l * 8 + hh] * 0.25f;
  return s;
}

__global__ void wprep_kernel(const float* __restrict__ W_in, const float* __restrict__ Wk,
                             const float* __restrict__ Wq, const float* __restrict__ Wv,
                             const float* __restrict__ att, const float* __restrict__ msg,
                             const float* __restrict__ pri, const float* __restrict__ Wa,
                             const float* __restrict__ W1, const float* __restrict__ W2,
                             _Float16* Wint, _Float16* Wcat, _Float16* Waf,
                             _Float16* W1f, _Float16* W2f) {
  int gid = blockIdx.x * 256 + threadIdx.x;
  float v;
  _Float16* dt;
  size_t o;
  if (gid < 16384) {
    int n = gid >> 7, k = gid & 127;
    v = W_in[k * 128 + n];
    dt = Wint; o = packA(n, k, 128);
  } else if (gid < 163840) {
    int t = gid - 16384;
    int l = t / 49152, u = t - l * 49152;
    int n = u >> 7, k = u & 127;
    v = fold_val(l, k, n, Wk, Wq, Wv, att, msg, pri);
    dt = Wcat + (size_t)l * 49152;
    o = packA(n, k, 128);
  } else if (gid < 212992) {
    int t = gid - 163840;
    int l = t / 16384, u = t & 16383;
    int n = u >> 7, k = u & 127;
    v = Wa[(size_t)l * 16384 + k * 128 + n];
    dt = Waf + (size_t)l * 16384;
    o = packA(n, k, 128);
  } else if (gid < 221184) {
    int u = gid - 212992;
    int n = u >> 7, k = u & 127;
    v = W1[k * 64 + n];
    dt = W1f; o = packA(n, k, 128);
  } else if (gid < 225280) {
    int u = gid - 221184;
    int n = u >> 6, k = u & 63;
    v = (n < 32) ? W2[k * 32 + n] : 0.f;
    dt = W2f; o = packA(n, k, 64);
  } else {
    return;
  }
  dt[o] = (_Float16)v;
}

// ---------------- CSR build (padded to multiple of 8 per node)
__global__ void hist_kernel(const int* __restrict__ dst, int* __restrict__ deg, int E) {
  int g = blockIdx.x * blockDim.x + threadIdx.x;
  if (g < E) atomicAdd(&deg[dst[g]], 1);
}

__global__ void scanA_kernel(const int* __restrict__ deg, int* __restrict__ offs,
                             int* __restrict__ bsum, int n) {
  __shared__ int sm[256];
  int t = threadIdx.x;
  int i = blockIdx.x * 256 + t;
  // pad each node's slot count to a multiple of 8 (half-wave chunk granularity)
  int v = (i < n) ? ((deg[i] + 7) & ~7) : 0;
  sm[t] = v;
  __syncthreads();
  for (int off = 1; off < 256; off <<= 1) {
    int u = (t >= off) ? sm[t - off] : 0;
    __syncthreads();
    sm[t] += u;
    __syncthreads();
  }
  if (i < n) offs[i] = sm[t] - v;
  if (t == 255) bsum[blockIdx.x] = sm[255];
}

__global__ void scanB_kernel(const int* __restrict__ bsum, int* __restrict__ boff,
                             int* __restrict__ offs, int nb, int n) {
  __shared__ int sm[256];
  int t = threadIdx.x;
  int v = (t < nb) ? bsum[t] : 0;
  sm[t] = v;
  __syncthreads();
  for (int off = 1; off < 256; off <<= 1) {
    int u = (t >= off) ? sm[t - off] : 0;
    __syncthreads();
    sm[t] += u;
    __syncthreads();
  }
  boff[t] = sm[t] - v;
  if (t == nb - 1) offs[n] = sm[t];
}

__global__ void scanC_kernel(int* __restrict__ offs, const int* __restrict__ boff,
                             int* __restrict__ cursor, int n) {
  int i = blockIdx.x * 256 + threadIdx.x;
  if (i < n) {
    int o = offs[i] + boff[blockIdx.x];
    offs[i] = o;
    cursor[i] = o;
  }
}

__global__ void scatter_kernel(const int* __restrict__ src, const int* __restrict__ dst,
                               const float* __restrict__ w, int* __restrict__ cursor,
                               int2* __restrict__ eld, int E) {
  int g = blockIdx.x * blockDim.x + threadIdx.x;
  if (g < E) {
    int d = dst[g];
    int p = atomicAdd(&cursor[d], 1);
    eld[p] = make_int2(src[g], __float_as_int(w[g]));
  }
}

// ---------------- fused layer kernel: GEMM1 (h) -> LDS fragments -> GEMM2 (kqv)
// FIRST=1: h = relu(x @ Wg1 + bias); FIRST=0: h = mix(agg @ Wg1, hold=hbuf) + relu
// then kqv = h @ Wcat -> kwmv/qbuf; h also written packed to hbuf (next layer's hold)
template <int FIRST>
__global__ __launch_bounds__(256) void fused_layer(
    const float* __restrict__ x, const _Float16* __restrict__ aggp,
    const _Float16* __restrict__ Wg1, const float* __restrict__ bias,
    const float* __restrict__ skipv, _Float16* __restrict__ hbuf,
    const _Float16* __restrict__ Wcat_l,
    _Float16* __restrict__ kwmv, _Float16* __restrict__ qbuf, int M) {
  int tid = threadIdx.x;
  int wave = tid >> 6, lane = tid & 63;
  int l16 = lane & 15, q = lane >> 4;
  int g = q, mloc = l16;
  int tile = blockIdx.x * 4 + wave;
  int m0 = tile * 16;
  bool alive = m0 < M;
  int tileC = alive ? tile : 0;

  __shared__ _Float16 htile_s[4][2048];
  __shared__ float ldsT_s[4][16 * 68];
  _Float16* htile = htile_s[wave];
  float* myT = ldsT_s[wave];

  // GEMM1 A fragments
  half8v a[4];
#pragma unroll
  for (int kc = 0; kc < 4; kc++) {
    if (FIRST) {
      int row = min(m0 + l16, M - 1);
      const float* p = x + (size_t)row * 128 + kc * 32 + q * 8;
      float4 u0 = *(const float4*)p, u1 = *(const float4*)(p + 4);
      float f[8] = {u0.x, u0.y, u0.z, u0.w, u1.x, u1.y, u1.z, u1.w};
      half8v hv;
#pragma unroll
      for (int i = 0; i < 8; i++) hv[i] = (_Float16)f[i];
      a[kc] = hv;
    } else {
      a[kc] = *(const half8v*)(aggp + (size_t)tileC * 2048 + (kc << 9) + lane * 8);
    }
  }

  float alpha = 1.f, beta = 0.f;
  if (!FIRST) {
    float sv = *skipv;
    alpha = 1.f / (1.f + __expf(-sv));
    beta = 1.f - alpha;
  }

  floatx4 acc1[8];
#pragma unroll
  for (int nt = 0; nt < 8; nt++) acc1[nt] = (floatx4){0.f, 0.f, 0.f, 0.f};
#pragma unroll
  for (int kc = 0; kc < 4; kc++) {
    half8v b[8];
#pragma unroll
    for (int nt = 0; nt < 8; nt++)
      b[nt] = *(const half8v*)(Wg1 + (size_t)nt * 2048 + (kc << 9) + lane * 8);
#pragma unroll
    for (int nt = 0; nt < 8; nt++)
      acc1[nt] = __builtin_amdgcn_mfma_f32_16x16x32_f16(a[kc], b[nt], acc1[nt], 0, 0, 0);
  }

  // epilogue1: per-64-col transpose; emit packed hbuf + LDS h-tile fragments
#pragma unroll
  for (int p = 0; p < 2; p++) {
    __syncthreads();
#pragma unroll
    for (int ntl = 0; ntl < 4; ntl++)
#pragma unroll
      for (int r = 0; r < 4; r++)
        myT[(q * 4 + r) * 68 + ntl * 16 + l16] = acc1[p * 4 + ntl][r];
    __syncthreads();
#pragma unroll
    for (int kc2 = 0; kc2 < 2; kc2++) {
      const float* rp = myT + mloc * 68 + kc2 * 32 + g * 8;
      floatx4 v0 = *(const floatx4*)rp;
      floatx4 v1 = *(const floatx4*)(rp + 4);
      float vals[8] = {v0[0], v0[1], v0[2], v0[3], v1[0], v1[1], v1[2], v1[3]};
      int col0 = p * 64 + kc2 * 32 + g * 8;
      size_t pbaseL = ((size_t)(tileC * 4 + (col0 >> 5)) << 9) + (size_t)lane * 8;
      if (FIRST) {
        float4 bb0 = *(const float4*)&bias[col0];
        float4 bb1 = *(const float4*)&bias[col0 + 4];
        float bbv[8] = {bb0.x, bb0.y, bb0.z, bb0.w, bb1.x, bb1.y, bb1.z, bb1.w};
#pragma unroll
        for (int j = 0; j < 8; j++) vals[j] = fmaxf(vals[j] + bbv[j], 0.f);
      } else {
        half8v hv = *(const half8v*)(hbuf + pbaseL);
#pragma unroll
        for (int j = 0; j < 8; j++)
          vals[j] = fmaxf(alpha * vals[j] + beta * (float)hv[j], 0.f);
      }
      half8v h8;
#pragma unroll
      for (int j = 0; j < 8; j++) h8[j] = (_Float16)vals[j];
      *(half8v*)(htile + (((p * 2 + kc2) << 9) + (g << 7) + (mloc << 3))) = h8;
      if (alive) *(half8v*)(hbuf + pbaseL) = h8;
    }
  }

  // GEMM2: kqv = h-tile @ Wcat (384 cols, 6 chunks of 64)
  for (int c = 0; c < 6; c++) {
    floatx4 acc2[4];
#pragma unroll
    for (int nt = 0; nt < 4; nt++) acc2[nt] = (floatx4){0.f, 0.f, 0.f, 0.f};
#pragma unroll
    for (int kc = 0; kc < 4; kc++) {
      half8v af = *(const half8v*)(htile + ((kc << 9) + lane * 8));
      half8v b[4];
#pragma unroll
      for (int nt = 0; nt < 4; nt++)
        b[nt] = *(const half8v*)(Wcat_l + (size_t)(c * 4 + nt) * 2048 + (kc << 9) + lane * 8);
#pragma unroll
      for (int nt = 0; nt < 4; nt++)
        acc2[nt] = __builtin_amdgcn_mfma_f32_16x16x32_f16(af, b[nt], acc2[nt], 0, 0, 0);
    }
    __syncthreads();
#pragma unroll
    for (int ntl = 0; ntl < 4; ntl++)
#pragma unroll
      for (int r = 0; r < 4; r++)
        myT[(q * 4 + r) * 68 + ntl * 16 + l16] = acc2[ntl][r];
    __syncthreads();
    if (alive) {
      int row = m0 + mloc;
#pragma unroll
      for (int kc2 = 0; kc2 < 2; kc2++) {
        const float* rp = myT + mloc * 68 + kc2 * 32 + g * 8;
        floatx4 v0 = *(const floatx4*)rp;
        floatx4 v1 = *(const floatx4*)(rp + 4);
        int col0 = c * 64 + kc2 * 32 + g * 8;
        int region = col0 >> 7;  // 0 kw, 1 q, 2 mv
        if (region == 1) {
          half8v h8;
#pragma unroll
          for (int j = 0; j < 4; j++) {
            h8[j] = (_Float16)v0[j];
            h8[j + 4] = (_Float16)v1[j];
          }
          *(half8v*)&qbuf[(size_t)row * 128 + (col0 - 128)] = h8;
        } else {
          int cc = col0 & 127;
          size_t base = (size_t)row * 256 + (size_t)(cc >> 2) * 8 + (region == 2 ? 4 : 0);
          half4v h0, h1;
#pragma unroll
          for (int j = 0; j < 4; j++) {
            h0[j] = (_Float16)v0[j];
            h1[j] = (_Float16)v1[j];
          }
          *(half4v*)&kwmv[base] = h0;
          *(half4v*)&kwmv[base + 8] = h1;
        }
      }
    }
  }
}

// ---------------- last Wa GEMM: hfinal = mix(agg @ Wa2, hold) (no relu) + hrow fp16
__global__ __launch_bounds__(256) void gemm_last(
    const _Float16* __restrict__ aggp, const _Float16* __restrict__ Wg1,
    const float* __restrict__ skipv, const _Float16* __restrict__ hbuf,
    float* __restrict__ hfinal, _Float16* __restrict__ hrow, int M) {
  int tid = threadIdx.x;
  int wave = tid >> 6, lane = tid & 63;
  int l16 = lane & 15, q = lane >> 4;
  int g = q, mloc = l16;
  int tile = blockIdx.x * 4 + wave;
  int m0 = tile * 16;
  bool alive = m0 < M;
  int tileC = alive ? tile : 0;

  __shared__ float ldsT_s[4][16 * 68];
  float* myT = ldsT_s[wave];

  half8v a[4];
#pragma unroll
  for (int kc = 0; kc < 4; kc++)
    a[kc] = *(const half8v*)(aggp + (size_t)tileC * 2048 + (kc << 9) + lane * 8);

  float sv = *skipv;
  float alpha = 1.f / (1.f + __expf(-sv));
  float beta = 1.f - alpha;

  floatx4 acc1[8];
#pragma unroll
  for (int nt = 0; nt < 8; nt++) acc1[nt] = (floatx4){0.f, 0.f, 0.f, 0.f};
#pragma unroll
  for (int kc = 0; kc < 4; kc++) {
    half8v b[8];
#pragma unroll
    for (int nt = 0; nt < 8; nt++)
      b[nt] = *(const half8v*)(Wg1 + (size_t)nt * 2048 + (kc << 9) + lane * 8);
#pragma unroll
    for (int nt = 0; nt < 8; nt++)
      acc1[nt] = __builtin_amdgcn_mfma_f32_16x16x32_f16(a[kc], b[nt], acc1[nt], 0, 0, 0);
  }

#pragma unroll
  for (int p = 0; p < 2; p++) {
    __syncthreads();
#pragma unroll
    for (int ntl = 0; ntl < 4; ntl++)
#pragma unroll
      for (int r = 0; r < 4; r++)
        myT[(q * 4 + r) * 68 + ntl * 16 + l16] = acc1[p * 4 + ntl][r];
    __syncthreads();
    if (alive) {
      int row = m0 + mloc;
#pragma unroll
      for (int kc2 = 0; kc2 < 2; kc2++) {
        const float* rp = myT + mloc * 68 + kc2 * 32 + g * 8;
        floatx4 v0 = *(const floatx4*)rp;
        floatx4 v1 = *(const floatx4*)(rp + 4);
        float vals[8] = {v0[0], v0[1], v0[2], v0[3], v1[0], v1[1], v1[2], v1[3]};
        int col0 = p * 64 + kc2 * 32 + g * 8;
        size_t pbase = ((size_t)(tile * 4 + (col0 >> 5)) << 9) + (size_t)lane * 8;
        half8v hv = *(const half8v*)(hbuf + pbase);
#pragma unroll
        for (int j = 0; j < 8; j++) vals[j] = alpha * vals[j] + beta * (float)hv[j];
        *(float4*)&hfinal[(size_t)row * 128 + col0] =
            make_float4(vals[0], vals[1], vals[2], vals[3]);
        *(float4*)&hfinal[(size_t)row * 128 + col0 + 4] =
            make_float4(vals[4], vals[5], vals[6], vals[7]);
        half8v h8;
#pragma unroll
        for (int j = 0; j < 8; j++) h8[j] = (_Float16)vals[j];
        *(half8v*)&hrow[(size_t)row * 128 + col0] = h8;
      }
    }
  }
}

// ---------------- fused predictor: Z=h[a]*h[b] -> W1+leaky -> W2+leaky -> dot W3
__global__ __launch_bounds__(256) void pred_fused(
    const _Float16* __restrict__ hrow,
    const int* __restrict__ ps, const int* __restrict__ pd,
    const int* __restrict__ ns, const int* __restrict__ nd,
    const _Float16* __restrict__ W1f, const float* __restrict__ b1,
    const _Float16* __restrict__ W2f, const float* __restrict__ b2,
    const float* __restrict__ W3, const float* __restrict__ b3,
    float* __restrict__ outd, int M) {
  int tid = threadIdx.x;
  int wave = tid >> 6, lane = tid & 63;
  int l16 = lane & 15, q = lane >> 4;
  int g = q, mloc = l16;
  int tile = blockIdx.x * 4 + wave;
  int m0 = tile * 16;
  bool alive = m0 < M;

  __shared__ _Float16 t1_s[4][1024];
  __shared__ float ldsT_s[4][16 * 68];
  _Float16* t1tile = t1_s[wave];
  float* myT = ldsT_s[wave];

  int gr = min(m0 + l16, M - 1);
  bool pos = gr < N_PAIRS;
  int idx = pos ? gr : gr - N_PAIRS;
  int pa = pos ? ps[idx] : ns[idx];
  int pb = pos ? pd[idx] : nd[idx];

  half8v a[4];
#pragma unroll
  for (int kc = 0; kc < 4; kc++) {
    int kbase = kc * 32 + q * 8;
    half8v ha = *(const half8v*)(hrow + (size_t)pa * 128 + kbase);
    half8v hb = *(const half8v*)(hrow + (size_t)pb * 128 + kbase);
    a[kc] = ha * hb;
  }

  floatx4 acc1[4];
#pragma unroll
  for (int nt = 0; nt < 4; nt++) acc1[nt] = (floatx4){0.f, 0.f, 0.f, 0.f};
#pragma unroll
  for (int kc = 0; kc < 4; kc++) {
    half8v b[4];
#pragma unroll
    for (int nt = 0; nt < 4; nt++)
      b[nt] = *(const half8v*)(W1f + (size_t)nt * 2048 + (kc << 9) + lane * 8);
#pragma unroll
    for (int nt = 0; nt < 4; nt++)
      acc1[nt] = __builtin_amdgcn_mfma_f32_16x16x32_f16(a[kc], b[nt], acc1[nt], 0, 0, 0);
  }

  // epilogue1: bias+leaky -> per-wave T1 fragments (16 rows x 64 k)
  __syncthreads();
#pragma unroll
  for (int ntl = 0; ntl < 4; ntl++)
#pragma unroll
    for (int r = 0; r < 4; r++)
      myT[(q * 4 + r) * 68 + ntl * 16 + l16] = acc1[ntl][r];
  __syncthreads();
#pragma unroll
  for (int kc2 = 0; kc2 < 2; kc2++) {
    const float* rp = myT + mloc * 68 + kc2 * 32 + g * 8;
    floatx4 v0 = *(const floatx4*)rp;
    floatx4 v1 = *(const floatx4*)(rp + 4);
    float vals[8] = {v0[0], v0[1], v0[2], v0[3], v1[0], v1[1], v1[2], v1[3]};
    int col0 = kc2 * 32 + g * 8;
    float4 bb0 = *(const float4*)&b1[col0];
    float4 bb1 = *(const float4*)&b1[col0 + 4];
    float bbv[8] = {bb0.x, bb0.y, bb0.z, bb0.w, bb1.x, bb1.y, bb1.z, bb1.w};
    half8v h8;
#pragma unroll
    for (int j = 0; j < 8; j++) {
      float v = vals[j] + bbv[j];
      v = v > 0.f ? v : 0.2f * v;
      h8[j] = (_Float16)v;
    }
    *(half8v*)(t1tile + ((kc2 << 9) + (g << 7) + (mloc << 3))) = h8;
  }

  // GEMM2: T1 @ W2 (K=64, N=32) + leaky + dot W3
  floatx4 acc2[2];
#pragma unroll
  for (int nt = 0; nt < 2; nt++) acc2[nt] = (floatx4){0.f, 0.f, 0.f, 0.f};
#pragma unroll
  for (int kc = 0; kc < 2; kc++) {
    half8v af = *(const half8v*)(t1tile + ((kc << 9) + lane * 8));
    half8v b[2];
#pragma unroll
    for (int nt = 0; nt < 2; nt++)
      b[nt] = *(const half8v*)(W2f + (size_t)nt * 1024 + (kc << 9) + lane * 8);
#pragma unroll
    for (int nt = 0; nt < 2; nt++)
      acc2[nt] = __builtin_amdgcn_mfma_f32_16x16x32_f16(af, b[nt], acc2[nt], 0, 0, 0);
  }

  float bw[2], wv[2];
#pragma unroll
  for (int nt = 0; nt < 2; nt++) {
    int col = nt * 16 + l16;
    bw[nt] = b2[col];
    wv[nt] = W3[col];
  }
  float b3v = b3[0];
#pragma unroll
  for (int r = 0; r < 4; r++) {
    float partial = 0.f;
#pragma unroll
    for (int nt = 0; nt < 2; nt++) {
      float v = acc2[nt][r] + bw[nt];
      v = v > 0.f ? v : 0.2f * v;
      partial += v * wv[nt];
    }
    partial += __shfl_xor(partial, 1);
    partial += __shfl_xor(partial, 2);
    partial += __shfl_xor(partial, 4);
    partial += __shfl_xor(partial, 8);
    int row = m0 + q * 4 + r;
    if (l16 == 0 && alive && row < M) outd[row] = partial + b3v;
  }
}

// ---------------- per-destination online-softmax aggregation
// one node per HALF-wave; explicit ping-pong depth-2 gather pipeline.
// __launch_bounds__(256,3) grants ~168 VGPR so both gather sets (64 VGPR)
// stay live; src-only meta in flight, edge weight reloaded lazily (L1-hot).
#define LOAD_SRC(J, S)                                                    \
  _Pragma("unroll") for (int i = 0; i < 8; i++) S[i] = esrc[((J) + i) * 2];

#define ISSUE_G(S, G)                                                     \
  _Pragma("unroll") for (int i = 0; i < 8; i++)                           \
      G[i] = *(const half8v*)&kwmv[(size_t)max(S[i], 0) * 256 + lofs];

#define COMPUTE(J, S, G)                                                     \
  {                                                                          \
    float p[8];                                                              \
    _Pragma("unroll") for (int i = 0; i < 8; i++) {                          \
      half2v k01 = {G[i][0], G[i][1]}, k23 = {G[i][2], G[i][3]};             \
      float d = __builtin_amdgcn_fdot2(                                      \
          k01, q01, __builtin_amdgcn_fdot2(k23, q23, 0.f, false), false);    \
      d += __shfl_xor(d, 1);                                                 \
      d += __shfl_xor(d, 2);                                                 \
      p[i] = (S[i] >= 0) ? d : -1e30f;                                       \
    }                                                                        \
    float nm = m;                                                            \
    _Pragma("unroll") for (int i = 0; i < 8; i++) nm = fmaxf(nm, p[i]);      \
    float sc = __expf(m - nm);                                               \
    float t[8], ssum = 0.f;                                                  \
    _Pragma("unroll") for (int i = 0; i < 8; i++) {                          \
      t[i] = __expf(p[i] - nm);                                              \
      ssum += t[i];                                                          \
    }                                                                        \
    s = s * sc + ssum;                                                       \
    a0 *= sc; a1 *= sc; a2 *= sc; a3 *= sc;                                  \
    _Pragma("unroll") for (int i = 0; i < 8; i++) {                          \
      float w = (S[i] >= 0) ? __int_as_float(esrc[((J) + i) * 2 + 1]) : 0.f; \
      float f = t[i] * w;                                                    \
      a0 += f * (float)G[i][4];                                              \
      a1 += f * (float)G[i][5];                                              \
      a2 += f * (float)G[i][6];                                              \
      a3 += f * (float)G[i][7];                                              \
    }                                                                        \
    m = nm;                                                                  \
  }

__global__ __launch_bounds__(256, 3) void edge_agg_kernel(
    const _Float16* __restrict__ kwmv, const _Float16* __restrict__ qbuf,
    const int* __restrict__ poffs, const int2* __restrict__ eld,
    _Float16* __restrict__ agg, int n) {
  int hw = (blockIdx.x * 256 + threadIdx.x) >> 5;  // half-wave stream id
  int stride = gridDim.x << 3;                     // half-waves in grid
  int c4 = threadIdx.x & 31;
  int ch = c4 << 2;
  size_t lofs = (size_t)c4 * 8;
  const int* esrc = (const int*)eld;  // slot i -> {src at 2i, wbits at 2i+1}
  for (int node = hw; node < n; node += stride) {
    half4v qv = *(const half4v*)&qbuf[(size_t)node * 128 + ch];
    half2v q01 = {qv[0], qv[1]}, q23 = {qv[2], qv[3]};
    float m = -1e30f, s = 0.f;
    float a0 = 0.f, a1 = 0.f, a2 = 0.f, a3 = 0.f;
    int beg = poffs[node], end = poffs[node + 1];
    if (beg < end) {
      int sA[8], sB[8], sA2[8], sB2[8];
      half8v gA[8], gB[8];
      // prologue: chunk0 + chunk1 (chunk1 may be past end -> sentinel region)
      LOAD_SRC(beg, sA);
      ISSUE_G(sA, gA);
      LOAD_SRC(beg + 8, sB);
      ISSUE_G(sB, gB);
      int j = beg;
      for (; j + 16 < end; j += 16) {
        // prefetch metas for chunks j+2, j+3 (may read past end: sentinel pad)
        LOAD_SRC(j + 16, sA2);
        LOAD_SRC(j + 24, sB2);
        COMPUTE(j, sA, gA);       // consume chunk j (gB, metas in flight)
        ISSUE_G(sA2, gA);         // refill A with chunk j+2
        COMPUTE(j + 8, sB, gB);   // consume chunk j+1 (new gA in flight)
        ISSUE_G(sB2, gB);         // refill B with chunk j+3
#pragma unroll
        for (int i = 0; i < 8; i++) {
          sA[i] = sA2[i];
          sB[i] = sB2[i];
        }
      }
      COMPUTE(j, sA, gA);
      if (j + 8 < end) COMPUTE(j + 8, sB, gB);
    }
    float inv = (s > 0.f) ? 1.f / s : 0.f;
    half4v out4;
    out4[0] = (_Float16)(a0 * inv);
    out4[1] = (_Float16)(a1 * inv);
    out4[2] = (_Float16)(a2 * inv);
    out4[3] = (_Float16)(a3 * inv);
    *(half4v*)&agg[packA(node, ch, 128)] = out4;
  }
}

extern "C" void kernel_launch(void* const* d_in, const int* in_sizes, int n_in,
                              void* d_out, int out_size, void* d_ws, size_t ws_size,
                              hipStream_t stream) {
  const float* x        = (const float*)d_in[0];
  const int*   edge_src = (const int*)d_in[1];
  const int*   edge_dst = (const int*)d_in[2];
  const float* edge_w   = (const float*)d_in[3];
  const int*   pos_src  = (const int*)d_in[4];
  const int*   pos_dst  = (const int*)d_in[5];
  const int*   neg_src  = (const int*)d_in[6];
  const int*   neg_dst  = (const int*)d_in[7];
  const float* W_in     = (const float*)d_in[8];
  const float* b_in     = (const float*)d_in[9];
  const float* Wk       = (const float*)d_in[10];
  const float* Wq       = (const float*)d_in[11];
  const float* Wv       = (const float*)d_in[12];
  const float* att_w    = (const float*)d_in[13];
  const float* msg_w    = (const float*)d_in[14];
  const float* pri      = (const float*)d_in[15];
  const float* Wa       = (const float*)d_in[16];
  const float* skip     = (const float*)d_in[17];
  const float* W1       = (const float*)d_in[18];
  const float* b1       = (const float*)d_in[19];
  const float* W2       = (const float*)d_in[20];
  const float* b2       = (const float*)d_in[21];
  const float* W3       = (const float*)d_in[22];
  const float* b3       = (const float*)d_in[23];
  float* out = (float*)d_out;

  // ---- workspace layout (bytes), ~91 MB
  char* W = (char*)d_ws;
  _Float16*  qbuf   = (_Float16*)(W + 0);          // 12,800,000
  _Float16*  kwmv   = (_Float16*)(W + 12800000);   // 25,600,000
  _Float16*  hbuf   = (_Float16*)(W + 38400000);   // 12,800,000 (packed h)
  _Float16*  agg    = (_Float16*)(W + 51200000);   // 12,800,000
  _Float16*  Wint   = (_Float16*)(W + 64000000);   // 32,768
  _Float16*  Wcat   = (_Float16*)(W + 64032768);   // 294,912
  _Float16*  Waf    = (_Float16*)(W + 64327680);   // 98,304
  _Float16*  W1f    = (_Float16*)(W + 64425984);   // 16,384
  _Float16*  W2f    = (_Float16*)(W + 64442368);   // 8,192
  int2*      eld    = (int2*)(W + 64450560);       // 12,800,000 (padded-8 edges)
  int*       deg    = (int*)(W + 77250560);        // 200,000
  int*       poffs  = (int*)(W + 77450560);        // 200,016
  int*       cursor = (int*)(W + 77650576);        // 200,000
  int*       bsum   = (int*)(W + 78050576);        // 1,024
  int*       boff   = (int*)(W + 78051600);        // 1,024
  _Float16*  hrow   = (_Float16*)(W + 78054912);   // 12,800,000 (fp16 row-major hfinal)
  float* hfinal = out + 2 * N_PAIRS;

  hipMemsetAsync(deg, 0, N_NODES * sizeof(int), stream);
  // sentinel: src=-1. pad-8 worst case: E + 7*N slots = 9.2MB (+prefetch overrun pad)
  hipMemsetAsync(eld, 0xFF, 9600000, stream);

  wprep_kernel<<<880, 256, 0, stream>>>(W_in, Wk, Wq, Wv, att_w, msg_w, pri, Wa, W1, W2,
                                        Wint, Wcat, Waf, W1f, W2f);
  hist_kernel<<<(N_EDGES + 255) / 256, 256, 0, stream>>>(edge_dst, deg, N_EDGES);
  scanA_kernel<<<196, 256, 0, stream>>>(deg, poffs, bsum, N_NODES);
  scanB_kernel<<<1, 256, 0, stream>>>(bsum, boff, poffs, 196, N_NODES);
  scanC_kernel<<<196, 256, 0, stream>>>(poffs, boff, cursor, N_NODES);
  scatter_kernel<<<(N_EDGES + 255) / 256, 256, 0, stream>>>(
      edge_src, edge_dst, edge_w, cursor, eld, N_EDGES);

  // layer 0: x -> h_in (relu proj) -> kqv0
  fused_layer<1><<<782, 256, 0, stream>>>(x, nullptr, Wint, b_in, nullptr, hbuf,
                                          Wcat, kwmv, qbuf, N_NODES);
  edge_agg_kernel<<<2048, 256, 0, stream>>>(kwmv, qbuf, poffs, eld, agg, N_NODES);
  // layer 1: agg0 -> h0 (skip-mix+relu) -> kqv1
  fused_layer<0><<<782, 256, 0, stream>>>(nullptr, agg, Waf, nullptr, skip + 0, hbuf,
                                          Wcat + 49152, kwmv, qbuf, N_NODES);
  edge_agg_kernel<<<2048, 256, 0, stream>>>(kwmv, qbuf, poffs, eld, agg, N_NODES);
  // layer 2: agg1 -> h1 (skip-mix+relu) -> kqv2
  fused_layer<0><<<782, 256, 0, stream>>>(nullptr, agg, Waf + 16384, nullptr, skip + 1,
                                          hbuf, Wcat + 98304, kwmv, qbuf, N_NODES);
  edge_agg_kernel<<<2048, 256, 0, stream>>>(kwmv, qbuf, poffs, eld, agg, N_NODES);
  // final: agg2 -> hfinal (skip-mix, no relu) + hrow fp16
  gemm_last<<<782, 256, 0, stream>>>(agg, Waf + 32768, skip + 2, hbuf,
                                     hfinal, hrow, N_NODES);
  // predictor (fully fused)
  pred_fused<<<3125, 256, 0, stream>>>(hrow, pos_src, pos_dst, neg_src, neg_dst,
                                       W1f, b1, W2f, b2, W3, b3, out, 2 * N_PAIRS);
}